// Round 10
// baseline (349.799 us; speedup 1.0000x reference)
//
#include <hip/hip_runtime.h>

#define NSP   25600   // 25*32*32 spatial elems per (b, channel)
#define HWC   1024    // 32*32

typedef __attribute__((ext_vector_type(8))) short bf8;   // 8 bf16 = 4 VGPRs
typedef __attribute__((ext_vector_type(4))) float f4;    // MFMA C/D frag
#define MFMA(a,b,c) __builtin_amdgcn_mfma_f32_16x16x32_bf16(a, b, c, 0, 0, 0)
typedef unsigned short u16;

__device__ __forceinline__ u16 f2b(float f) {
    union { float f; unsigned u; } v; v.f = f;
    unsigned r = v.u + 0x7fffu + ((v.u >> 16) & 1u);
    return (u16)(r >> 16);
}
__device__ __forceinline__ float b2f(u16 h) {
    union { unsigned u; float f; } v; v.u = ((unsigned)h) << 16;
    return v.f;
}

// Attention addressing (K re-chunked into 32-contig-elem blocks; legal since
// fold K-order only needs consistency between q/k/v/unfold).
__device__ __forceinline__ long row_base(int att, int b, int m) {
    if (att == 0) { int cc = m >> 5, h = m & 31;   return ((long)(b*128 + cc))*NSP + h*32; }
    else if (att == 1) { int cc = m / 5, u = m - cc*5; return ((long)(b*128 + 32 + cc))*NSP + u*5120; }
    else { int h = m / 5, u = m - h*5;            return ((long)(b*128 + 64))*NSP + u*5120 + h*32; }
}
__device__ __forceinline__ long chunk_off(int att, int kc) {
    if (att == 0) return (long)kc * 1024;
    else if (att == 1) return (long)kc * 32;
    else { int cc = kc / 5, v = kc - cc*5; return (long)cc*NSP + v*1024; }
}

// ---------------- K0: one-time weight convert to bf16 transposed -----------
__global__ __launch_bounds__(256) void k_prep(
        const float* __restrict__ Wi, const float* __restrict__ Wk,
        const float* __restrict__ W1, const float* __restrict__ W2,
        const float* __restrict__ Wo, u16* __restrict__ wbt) {
    int e = blockIdx.x * 256 + threadIdx.x;      // 57344 total
    const float* src; int base, K, N;
    if (e < 8192)       { src = Wi; base = 0;     K = 64;  N = 128; }
    else if (e < 16384) { src = Wk; base = 8192;  K = 64;  N = 128; }
    else if (e < 32768) { src = W1; base = 16384; K = 128; N = 128; }
    else if (e < 49152) { src = W2; base = 32768; K = 128; N = 128; }
    else                { src = Wo; base = 49152; K = 128; N = 64;  }
    int local = e - base, n = local / K, k = local - n * K;
    wbt[e] = f2b(src[k * N + n]);
}

// ---------------- K1: token GEMMs (MFMA) -> bf16 q / kv --------------------
__global__ __launch_bounds__(256) void k_tokens(
        const float* __restrict__ x_hf, const float* __restrict__ x_lf,
        const u16* __restrict__ wbt,
        u16* __restrict__ qb, u16* __restrict__ kvb) {
    // grid (400, 4, 2)
    int s0 = blockIdx.x * 64, b = blockIdx.y, which = blockIdx.z;
    const float* x  = which ? x_lf : x_hf;
    const u16* Wb = wbt + (which ? 8192 : 0);    // [d][c] bf16
    u16* out = which ? kvb : qb;
    __shared__ u16 Axs[64 * 72];   // [token][c]
    __shared__ u16 Wl [128 * 72];  // [d][c]
    int tid = threadIdx.x;
    for (int g = tid; g < 1024; g += 256) {      // W stage: 16B contiguous
        int d = g >> 3, c8 = (g & 7) * 8;
        *(bf8*)&Wl[d * 72 + c8] = *(const bf8*)(Wb + d * 64 + c8);
    }
    for (int g = tid; g < 1024; g += 256) {      // x transpose, packed x4
        int s = g & 63, c4 = (g >> 6) * 4;
        long xb = ((long)(b * 64 + c4)) * NSP + s0 + s;
        ushort4 pk;
        pk.x = f2b(x[xb]);
        pk.y = f2b(x[xb + NSP]);
        pk.z = f2b(x[xb + 2 * NSP]);
        pk.w = f2b(x[xb + 3 * NSP]);
        *(ushort4*)&Axs[s * 72 + c4] = pk;
    }
    __syncthreads();
    int w = tid >> 6, l = tid & 63, quad = l >> 4, col = l & 15;
    f4 z = {0.f, 0.f, 0.f, 0.f};
    f4 acc[8]; for (int i = 0; i < 8; ++i) acc[i] = z;
#pragma unroll
    for (int kc = 0; kc < 2; ++kc) {
        bf8 a = *(bf8*)&Axs[(w * 16 + col) * 72 + kc * 32 + quad * 8];
#pragma unroll
        for (int nt = 0; nt < 8; ++nt) {
            bf8 bb = *(bf8*)&Wl[(nt * 16 + col) * 72 + kc * 32 + quad * 8];
            acc[nt] = MFMA(a, bb, acc[nt]);
        }
    }
#pragma unroll
    for (int nt = 0; nt < 8; ++nt) {
        int d = nt * 16 + col;
        long base = ((long)(b * 128 + d)) * NSP + s0 + w * 16 + quad * 4;
        ushort4 pk;
        pk.x = f2b(acc[nt][0]); pk.y = f2b(acc[nt][1]);
        pk.z = f2b(acc[nt][2]); pk.w = f2b(acc[nt][3]);
        *(ushort4*)(out + base) = pk;
    }
}

// ---------------- K2: fused V^T transposes + L2 norms ----------------------
__global__ __launch_bounds__(256) void k_vt_norms(
        const u16* __restrict__ qb, const u16* __restrict__ kvb,
        u16* __restrict__ vt0, u16* __restrict__ vt1, u16* __restrict__ vt2,
        float* __restrict__ nq, float* __restrict__ nk) {
    // grid (5888, 4): x<3200 -> vt tiles; else norms rows
    int x = blockIdx.x, b = blockIdx.y;
    int tid = threadIdx.x;
    if (x < 3200) {
        int att, kc, pt, P, KC; u16* vt;
        if (x < 800)       { att = 0; kc = x >> 5; pt = (x & 31) * 32; P = 1024; KC = 25;  vt = vt0; }
        else if (x < 1600) { int x2 = x - 800;  att = 1; kc = x2 / 5; pt = (x2 - kc * 5) * 32; P = 160; KC = 160; vt = vt1; }
        else               { int x3 = x - 1600; att = 2; kc = x3 / 5; pt = (x3 - kc * 5) * 32; P = 160; KC = 320; vt = vt2; }
        long co = chunk_off(att, kc);
        __shared__ u16 T[32 * 36];
        {
            int r = tid >> 3, fq = (tid & 7) * 4;
            ushort4 e = *(const ushort4*)(kvb + row_base(att, b, pt + r) + co + fq);
            *(ushort4*)&T[r * 36 + fq] = e;
        }
        __syncthreads();
        {
            int f = tid >> 3, p4 = (tid & 7) * 4;
            ushort4 pk;
            pk.x = T[(p4    ) * 36 + f];
            pk.y = T[(p4 + 1) * 36 + f];
            pk.z = T[(p4 + 2) * 36 + f];
            pk.w = T[(p4 + 3) * 36 + f];
            *(ushort4*)(vt + ((long)b * KC + kc) * 32 * P + (long)f * P + pt + p4) = pk;
        }
    } else {
        int x2 = x - 3200;                       // 0..2687
        int which = x2 >= 1344;
        int xm = which ? x2 - 1344 : x2;
        int att, m, KC, off;
        if (xm < 1024)      { att = 0; m = xm;        KC = 25;  off = b * 1024 + m; }
        else if (xm < 1184) { att = 1; m = xm - 1024; KC = 160; off = 4096 + b * 160 + m; }
        else                { att = 2; m = xm - 1184; KC = 320; off = 4736 + b * 160 + m; }
        const u16* src = which ? kvb : qb;
        float* dst = which ? nk : nq;
        long base = row_base(att, b, m);
        float s = 0.f;
        int K = KC * 32;
        for (int k = tid; k < K; k += 256) {
            float v = b2f(src[base + chunk_off(att, k >> 5) + (k & 31)]);
            s += v * v;
        }
        __shared__ float red[256];
        red[tid] = s; __syncthreads();
        for (int w = 128; w >= 1; w >>= 1) {
            if (tid < w) red[tid] += red[tid + w];
            __syncthreads();
        }
        if (tid == 0) dst[off] = fmaxf(sqrtf(red[0]), 1e-12f);
    }
}

// ---------------- K3: fused S-GEMMs (att0 tiled + att1/2 split-K) ----------
__global__ __launch_bounds__(256) void k_sgemm_all(
        const u16* __restrict__ qb, const u16* __restrict__ kvb,
        const float* __restrict__ nq, const float* __restrict__ nk,
        u16* __restrict__ Sb, float* __restrict__ Spart) {
    // grid (586, 4): x<136 -> att0 triangular 64x64 tile; else split-K
    __shared__ float lds[4096];
    int x = blockIdx.x, b = blockIdx.y;
    int tid = threadIdx.x, w = tid >> 6, l = tid & 63, quad = l >> 4, col = l & 15;
    if (x < 136) {
        u16* Qs = (u16*)lds;          // 64*40
        u16* Ks = Qs + 64 * 40;
        int t = x, i = 0;
        while (t >= (i + 1) * (i + 2) / 2) ++i;
        int j = t - i * (i + 1) / 2;
        int mt = i * 64, nt = j * 64;
        int srow = tid >> 2, g = tid & 3;
        f4 z = {0.f, 0.f, 0.f, 0.f};
        f4 acc[4]; for (int q = 0; q < 4; ++q) acc[q] = z;
        for (int kc = 0; kc < 25; ++kc) {
            long co = (long)kc * 1024;
            {
                int m = mt + srow;
                *(bf8*)&Qs[srow * 40 + g * 8] =
                    *(const bf8*)(qb + ((long)(b*128 + (m >> 5)))*NSP + (m & 31)*32 + co + g*8);
                int n = nt + srow;
                *(bf8*)&Ks[srow * 40 + g * 8] =
                    *(const bf8*)(kvb + ((long)(b*128 + (n >> 5)))*NSP + (n & 31)*32 + co + g*8);
            }
            __syncthreads();
            bf8 a = *(bf8*)&Qs[(w * 16 + col) * 40 + quad * 8];
#pragma unroll
            for (int t2 = 0; t2 < 4; ++t2) {
                bf8 bb = *(bf8*)&Ks[(t2 * 16 + col) * 40 + quad * 8];
                acc[t2] = MFMA(a, bb, acc[t2]);
            }
            __syncthreads();
        }
#pragma unroll
        for (int t2 = 0; t2 < 4; ++t2)
#pragma unroll
            for (int r = 0; r < 4; ++r) {
                int m = mt + w * 16 + quad * 4 + r, n = nt + t2 * 16 + col;
                float v = (n <= m) ? acc[t2][r] / (nq[b*1024 + m] * nk[b*1024 + n]) : 0.f;
                Sb[((long)b * 1024 + m) * 1024 + n] = f2b(v);
            }
    } else {
        int x2 = x - 136;                        // 0..449
        int t = x2 % 15, y = x2 / 15;            // y 0..29
        int att, split, nsplit; float* base;
        if (y < 10) { att = 1; split = y;      nsplit = 10; base = Spart; }
        else        { att = 2; split = y - 10; nsplit = 20; base = Spart + 614400; }
        int i = 0;
        while (t >= (i + 1) * (i + 2) / 2) ++i;
        int j = t - i * (i + 1) / 2;
        int mt = i * 32, nt = j * 32;
        long rm0 = row_base(att, b, mt + col),      rm1 = row_base(att, b, mt + 16 + col);
        long rn0 = row_base(att, b, nt + col),      rn1 = row_base(att, b, nt + 16 + col);
        int ko = quad * 8;
        f4 z = {0.f, 0.f, 0.f, 0.f};
        f4 a00 = z, a01 = z, a10 = z, a11 = z;
#pragma unroll
        for (int s = 0; s < 4; ++s) {
            int kc = split * 16 + w * 4 + s;
            long co = chunk_off(att, kc);
            bf8 qa0 = *(const bf8*)(qb + rm0 + co + ko);
            bf8 qa1 = *(const bf8*)(qb + rm1 + co + ko);
            bf8 kb0 = *(const bf8*)(kvb + rn0 + co + ko);
            bf8 kb1 = *(const bf8*)(kvb + rn1 + co + ko);
            a00 = MFMA(qa0, kb0, a00); a01 = MFMA(qa0, kb1, a01);
            a10 = MFMA(qa1, kb0, a10); a11 = MFMA(qa1, kb1, a11);
        }
        float* my = lds + w * 1024;
#pragma unroll
        for (int r = 0; r < 4; ++r) {
            my[(quad * 4 + r) * 32 + col]            = a00[r];
            my[(quad * 4 + r) * 32 + 16 + col]       = a01[r];
            my[(16 + quad * 4 + r) * 32 + col]       = a10[r];
            my[(16 + quad * 4 + r) * 32 + 16 + col]  = a11[r];
        }
        __syncthreads();
        float* dst = base + ((long)((b * 15 + t) * nsplit + split)) * 1024;
        for (int e = tid; e < 1024; e += 256)
            dst[e] = lds[e] + lds[1024 + e] + lds[2048 + e] + lds[3072 + e];
    }
}

// ---------------- K4: fused softmaxes --------------------------------------
__global__ __launch_bounds__(256) void k_softmax_all(
        const u16* __restrict__ Sb, u16* __restrict__ Pb,
        const float* __restrict__ Spart, const float* __restrict__ nq,
        const float* __restrict__ nk, u16* __restrict__ Pb12) {
    // grid (576, 4): x<256 -> att0 wave-per-row; else att1/2 column softmax
    int xb = blockIdx.x, b = blockIdx.y, tid = threadIdx.x;
    if (xb < 256) {
        int w = tid >> 6, lane = tid & 63;
        int m = xb * 4 + w;
        const u16* row = Sb + ((long)b * 1024 + m) * 1024;
        u16* pr = Pb + ((long)b * 1024 + m) * 1024;
        int e0 = lane * 16;
        bf8 x0 = *(const bf8*)(row + e0);
        bf8 x1 = *(const bf8*)(row + e0 + 8);
        float v[16];
#pragma unroll
        for (int j = 0; j < 8; ++j) { v[j] = b2f(((u16*)&x0)[j]); v[8 + j] = b2f(((u16*)&x1)[j]); }
        float mx = -1e30f;
#pragma unroll
        for (int j = 0; j < 16; ++j) if (e0 + j <= m) mx = fmaxf(mx, v[j]);
#pragma unroll
        for (int o = 32; o >= 1; o >>= 1) mx = fmaxf(mx, __shfl_xor(mx, o));
        float s = 0.f;
#pragma unroll
        for (int j = 0; j < 16; ++j) {
            float e = (e0 + j <= m) ? __expf(v[j] - mx) : 0.f;
            v[j] = e; s += e;
        }
#pragma unroll
        for (int o = 32; o >= 1; o >>= 1) s += __shfl_xor(s, o);
        float inv = 1.f / s;
        bf8 o0, o1;
#pragma unroll
        for (int j = 0; j < 8; ++j) {
            ((u16*)&o0)[j] = f2b(v[j] * inv);
            ((u16*)&o1)[j] = f2b(v[8 + j] * inv);
        }
        *(bf8*)(pr + e0) = o0;
        *(bf8*)(pr + e0 + 8) = o1;
    } else {
        int x = xb - 256;                        // 0..319
        int att = (x < 160) ? 1 : 2;
        int m = (att == 1) ? x : x - 160;
        int nsplit = (att == 1) ? 10 : 20;
        const float* base = (att == 1) ? Spart : Spart + 614400;
        int noff = (att == 1) ? 4096 : 4736;
        u16* P = Pb12 + ((att == 1) ? 0 : 102400);
        int i = m >> 5, ro = (m & 31) * 32;
        int n = tid;
        bool act = (n <= m) && (n < 160);
        float myv = 0.f;
        if (act) {
            int t = i * (i + 1) / 2 + (n >> 5);
            const float* src = base + ((long)((b * 15 + t) * nsplit)) * 1024 + ro + (n & 31);
            float s = 0.f;
            for (int sp = 0; sp < nsplit; ++sp) s += src[(long)sp * 1024];
            myv = s / (nq[noff + b * 160 + m] * nk[noff + b * 160 + n]);
        }
        __shared__ float red[256];
        red[tid] = act ? myv : -1e30f; __syncthreads();
        for (int w = 128; w >= 1; w >>= 1) {
            if (tid < w) red[tid] = fmaxf(red[tid], red[tid + w]);
            __syncthreads();
        }
        float mx = red[0]; __syncthreads();
        float e = act ? __expf(myv - mx) : 0.f;
        red[tid] = e; __syncthreads();
        for (int w = 128; w >= 1; w >>= 1) {
            if (tid < w) red[tid] += red[tid + w];
            __syncthreads();
        }
        float inv = 1.f / red[0];
        if (n < 160) P[((long)b * 160 + m) * 160 + n] = f2b(e * inv);
    }
}

// ---------------- K5: fused O-GEMMs + residual (restructured R10) ----------
// att0: block = 64 m-rows x 160 features (5 kc), K-slab 64 p per barrier
//       -> 20 MFMA/wave/barrier, P refetched 5x not 25x.
// att1/2: stage all chunks once -> single barrier pair per block.
__global__ __launch_bounds__(256) void k_ogemm_all(
        const u16* __restrict__ Pb, const u16* __restrict__ vt0,
        const u16* __restrict__ Pb12, const u16* __restrict__ vt1,
        const u16* __restrict__ vt2, const u16* __restrict__ kvb,
        u16* __restrict__ catb) {
    // grid (2480, 4): x<80 -> att0 (mtt = x&15, kcg = x>>4); else att1/2
    __shared__ u16 lds[16128];     // 32,256 B
    int x = blockIdx.x, b = blockIdx.y;
    int tid = threadIdx.x, w = tid >> 6, l = tid & 63, quad = l >> 4, col = l & 15;
    if (x < 80) {
        int mtt = x & 15, kcg = x >> 4;          // kcg 0..4
        int mt = mtt * 64;
        u16* Ps = lds;              // 64 x 72 (rows m-local, cols p-slab)
        u16* Vs = lds + 64 * 72;    // 160 x 72 (rows f-local, cols p-slab)
        const u16* vbase = vt0 + ((long)(b * 25 + kcg * 5)) * 32 * 1024;
        f4 z = {0.f, 0.f, 0.f, 0.f};
        f4 acc[10];
#pragma unroll
        for (int i = 0; i < 10; ++i) acc[i] = z;
        int iters = mtt + 1;                     // covers p = 0 .. mt+64
        for (int s = 0; s < iters; ++s) {
            int c0 = s * 64;
#pragma unroll
            for (int i = 0; i < 2; ++i) {        // P stage: 64x64
                int idx = i * 256 + tid;
                int row = idx >> 3, c8 = (idx & 7) * 8;
                *(bf8*)&Ps[row * 72 + c8] =
                    *(const bf8*)(Pb + ((long)(b * 1024 + mt + row)) * 1024 + c0 + c8);
            }
#pragma unroll
            for (int i = 0; i < 5; ++i) {        // V stage: 160x64
                int idx = i * 256 + tid;
                int f = idx >> 3, p8 = (idx & 7) * 8;
                *(bf8*)&Vs[f * 72 + p8] =
                    *(const bf8*)(vbase + (long)f * 1024 + c0 + p8);
            }
            __syncthreads();
            bf8 a0 = *(bf8*)&Ps[(w * 16 + col) * 72 + quad * 8];
            bf8 a1 = *(bf8*)&Ps[(w * 16 + col) * 72 + 32 + quad * 8];
#pragma unroll
            for (int ft = 0; ft < 10; ++ft) {
                bf8 b0 = *(bf8*)&Vs[(ft * 16 + col) * 72 + quad * 8];
                bf8 b1 = *(bf8*)&Vs[(ft * 16 + col) * 72 + 32 + quad * 8];
                acc[ft] = MFMA(a0, b0, acc[ft]);
                acc[ft] = MFMA(a1, b1, acc[ft]);
            }
            __syncthreads();
        }
#pragma unroll
        for (int ft = 0; ft < 10; ++ft) {
            int kc = kcg * 5 + (ft >> 1);
            int f_in = (ft & 1) * 16 + col;
            long co = (long)kc * 1024;
#pragma unroll
            for (int r = 0; r < 4; ++r) {
                int m = mt + w * 16 + quad * 4 + r;
                long adr = ((long)(b * 128 + (m >> 5))) * NSP + (m & 31) * 32 + co + f_in;
                catb[adr] = f2b(acc[ft][r] + b2f(kvb[adr]));
            }
        }
    } else {
        int x2 = x - 80;                         // 0..2399
        int it = x2 % 5, y = x2 / 5;             // y 0..479
        int att, kc, KC; const u16 *vt, *P;
        if (y < 160) { att = 1; kc = y;       KC = 160; vt = vt1; P = Pb12; }
        else         { att = 2; kc = y - 160; KC = 320; vt = vt2; P = Pb12 + 102400; }
        int mt = it * 32;
        const u16* vtc = vt + ((long)b * KC + kc) * 32 * 160;
        u16* Ps = lds;                 // 32 x 168 (rows m-local, cols n)
        u16* Vs = lds + 32 * 168;      // 32 x 168 (rows f, cols n=p)
        int row = tid >> 3, g4 = (tid & 7) * 4;
        for (int nt2 = 0; nt2 <= it; ++nt2) {    // stage all chunks, no barriers
            *(ushort4*)&Ps[row * 168 + nt2 * 32 + g4] =
                *(const ushort4*)(P + ((long)(b * 160 + mt + row)) * 160 + nt2 * 32 + g4);
            *(ushort4*)&Vs[row * 168 + nt2 * 32 + g4] =
                *(const ushort4*)(vtc + (long)row * 160 + nt2 * 32 + g4);
        }
        __syncthreads();
        int mh = w & 1, fh = w >> 1;
        f4 acc = {0.f, 0.f, 0.f, 0.f};
        for (int ks = 0; ks <= it; ++ks) {
            bf8 a  = *(bf8*)&Ps[(mh * 16 + col) * 168 + ks * 32 + quad * 8];
            bf8 bb = *(bf8*)&Vs[(fh * 16 + col) * 168 + ks * 32 + quad * 8];
            acc = MFMA(a, bb, acc);
        }
#pragma unroll
        for (int r = 0; r < 4; ++r) {
            int m = mt + mh * 16 + quad * 4 + r, f = fh * 16 + col;
            long adr = row_base(att, b, m) + chunk_off(att, kc) + f;
            catb[adr] = f2b(acc[r] + b2f(kvb[adr]));
        }
    }
}

// ---------------- K6: transpose cat -> ct + fused LN stats -----------------
__global__ __launch_bounds__(256) void k_transpose_ln(
        const u16* __restrict__ catb, u16* __restrict__ ctb,
        float* __restrict__ mu, float* __restrict__ rstd) {
    // grid (64, 100): 16 tokens (hw) x 128 d per block
    int hwt = blockIdx.x * 16, bn = blockIdx.y;
    int b = bn / 25, uv = bn - b * 25;
    __shared__ u16 T[16 * 136];
    int tid = threadIdx.x;
    const u16* src = catb + (long)b * 128 * NSP + (long)uv * HWC + hwt;
    {
        int d = tid >> 1, hw8 = (tid & 1) * 8;
        bf8 v = *(const bf8*)(src + (long)d * NSP + hw8);
#pragma unroll
        for (int j = 0; j < 8; ++j) T[(hw8 + j) * 136 + d] = ((u16*)&v)[j];
    }
    __syncthreads();
    {
        int w = tid >> 6, l = tid & 63;
        int tk = w * 4 + (l >> 4), dg = (l & 15) * 8;
        bf8 vv = *(bf8*)&T[tk * 136 + dg];
        float s = 0.f, s2 = 0.f;
#pragma unroll
        for (int j = 0; j < 8; ++j) {
            float f = b2f(((u16*)&vv)[j]); s += f; s2 += f * f;
        }
        for (int o = 8; o >= 1; o >>= 1) { s += __shfl_xor(s, o); s2 += __shfl_xor(s2, o); }
        if ((l & 15) == 0) {
            int t = bn * 1024 + hwt + tk;
            float m = s * (1.f / 128.f);
            float var = s2 * (1.f / 128.f) - m * m;
            mu[t] = m; rstd[t] = rsqrtf(var + 1e-5f);
        }
    }
    {
        int hw = tid >> 4, d8 = (tid & 15) * 8;
        *(bf8*)(ctb + ((long)(bn * 1024 + hwt + hw)) * 128 + d8) = *(bf8*)&T[hw * 136 + d8];
    }
}

// ---------------- K8: h1 = relu(LN(ct) @ W1) (MFMA) ------------------------
__global__ __launch_bounds__(256) void k_mlp1(
        const u16* __restrict__ ctb, const float* __restrict__ mu,
        const float* __restrict__ rstd, const float* __restrict__ g,
        const float* __restrict__ be, const u16* __restrict__ wbt,
        u16* __restrict__ h1b) {
    int tt = blockIdx.x * 64, tid = threadIdx.x;
    const u16* W1b = wbt + 16384;                // [n][k] 128x128
    __shared__ u16 As[64 * 136], Wt[128 * 136];
    __shared__ float gl[128], bl[128];
    if (tid < 128) { gl[tid] = g[tid]; bl[tid] = be[tid]; }
    for (int q = tid; q < 2048; q += 256) {      // W stage: 16B contiguous
        int n = q >> 4, k8 = (q & 15) * 8;
        *(bf8*)&Wt[n * 136 + k8] = *(const bf8*)(W1b + n * 128 + k8);
    }
    __syncthreads();                             // gl/bl visible
    for (int q = tid; q < 1024; q += 256) {      // A: LN transform, bf8
        int row = q >> 4, k8 = (q & 15) * 8, t = tt + row;
        bf8 cv = *(const bf8*)(ctb + (long)t * 128 + k8);
        float m = mu[t], rs = rstd[t];
        bf8 av;
#pragma unroll
        for (int j = 0; j < 8; ++j)
            ((u16*)&av)[j] = f2b((b2f(((u16*)&cv)[j]) - m) * rs * gl[k8 + j] + bl[k8 + j]);
        *(bf8*)&As[row * 136 + k8] = av;
    }
    __syncthreads();
    int w = tid >> 6, l = tid & 63, quad = l >> 4, col = l & 15;
    f4 z = {0.f, 0.f, 0.f, 0.f};
    f4 acc[8]; for (int i = 0; i < 8; ++i) acc[i] = z;
#pragma unroll
    for (int kc = 0; kc < 4; ++kc) {
        bf8 a = *(bf8*)&As[(w * 16 + col) * 136 + kc * 32 + quad * 8];
#pragma unroll
        for (int nt = 0; nt < 8; ++nt) {
            bf8 bb = *(bf8*)&Wt[(nt * 16 + col) * 136 + kc * 32 + quad * 8];
            acc[nt] = MFMA(a, bb, acc[nt]);
        }
    }
#pragma unroll
    for (int nt = 0; nt < 8; ++nt)
#pragma unroll
        for (int r = 0; r < 4; ++r) {
            int t = tt + w * 16 + quad * 4 + r, n = nt * 16 + col;
            h1b[(long)t * 128 + n] = f2b(fmaxf(acc[nt][r], 0.f));
        }
}

// ---------------- K9: m2 = h1 @ W2 + ct (MFMA) -----------------------------
__global__ __launch_bounds__(256) void k_mlp2(
        const u16* __restrict__ h1b, const u16* __restrict__ ctb,
        const u16* __restrict__ wbt, u16* __restrict__ m2b) {
    int tt = blockIdx.x * 64, tid = threadIdx.x;
    const u16* W2b = wbt + 32768;                // [n][k] 128x128
    __shared__ u16 As[64 * 136], Wt[128 * 136];
    for (int q = tid; q < 2048; q += 256) {
        int n = q >> 4, k8 = (q & 15) * 8;
        *(bf8*)&Wt[n * 136 + k8] = *(const bf8*)(W2b + n * 128 + k8);
    }
    for (int q = tid; q < 1024; q += 256) {
        int row = q >> 4, k8 = (q & 15) * 8;
        *(bf8*)&As[row * 136 + k8] = *(const bf8*)(h1b + (long)(tt + row) * 128 + k8);
    }
    __syncthreads();
    int w = tid >> 6, l = tid & 63, quad = l >> 4, col = l & 15;
    f4 z = {0.f, 0.f, 0.f, 0.f};
    f4 acc[8]; for (int i = 0; i < 8; ++i) acc[i] = z;
#pragma unroll
    for (int kc = 0; kc < 4; ++kc) {
        bf8 a = *(bf8*)&As[(w * 16 + col) * 136 + kc * 32 + quad * 8];
#pragma unroll
        for (int nt = 0; nt < 8; ++nt) {
            bf8 bb = *(bf8*)&Wt[(nt * 16 + col) * 136 + kc * 32 + quad * 8];
            acc[nt] = MFMA(a, bb, acc[nt]);
        }
    }
#pragma unroll
    for (int nt = 0; nt < 8; ++nt)
#pragma unroll
        for (int r = 0; r < 4; ++r) {
            int t = tt + w * 16 + quad * 4 + r, n = nt * 16 + col;
            m2b[(long)t * 128 + n] = f2b(acc[nt][r] + b2f(ctb[(long)t * 128 + n]));
        }
}

// ---------------- K10: out = m2 @ W_out (MFMA), scatter --------------------
__global__ __launch_bounds__(256) void k_out(
        const u16* __restrict__ m2b, const u16* __restrict__ wbt,
        float* __restrict__ out) {
    int tt = blockIdx.x * 64, tid = threadIdx.x;
    const u16* Wob = wbt + 49152;                // [o][k] 64x128
    __shared__ u16 As[64 * 136], Wt[64 * 136];
    for (int q = tid; q < 1024; q += 256) {
        int o = q >> 4, k8 = (q & 15) * 8;
        *(bf8*)&Wt[o * 136 + k8] = *(const bf8*)(Wob + o * 128 + k8);
    }
    for (int q = tid; q < 1024; q += 256) {
        int row = q >> 4, k8 = (q & 15) * 8;
        *(bf8*)&As[row * 136 + k8] = *(const bf8*)(m2b + (long)(tt + row) * 128 + k8);
    }
    __syncthreads();
    int w = tid >> 6, l = tid & 63, quad = l >> 4, col = l & 15;
    f4 z = {0.f, 0.f, 0.f, 0.f};
    f4 acc[4]; for (int i = 0; i < 4; ++i) acc[i] = z;
#pragma unroll
    for (int kc = 0; kc < 4; ++kc) {
        bf8 a = *(bf8*)&As[(w * 16 + col) * 136 + kc * 32 + quad * 8];
#pragma unroll
        for (int nt = 0; nt < 4; ++nt) {
            bf8 bb = *(bf8*)&Wt[(nt * 16 + col) * 136 + kc * 32 + quad * 8];
            acc[nt] = MFMA(a, bb, acc[nt]);
        }
    }
    int t0 = tt + w * 16 + quad * 4;
    int bn = t0 >> 10, hw = t0 & 1023;
    int b = bn / 25, uv = bn - b * 25;
#pragma unroll
    for (int nt = 0; nt < 4; ++nt) {
        int o = nt * 16 + col;
        float4 pk = {acc[nt][0], acc[nt][1], acc[nt][2], acc[nt][3]};
        *(float4*)(out + ((long)((b * 64 + o) * 25 + uv)) * 1024 + hw) = pk;
    }
}

// ---------------- launch ---------------------------------------------------
extern "C" void kernel_launch(void* const* d_in, const int* in_sizes, int n_in,
                              void* d_out, int out_size, void* d_ws, size_t ws_size,
                              hipStream_t stream) {
    const float* x_lf = (const float*)d_in[0];
    const float* x_hf = (const float*)d_in[1];
    const float* W_in = (const float*)d_in[2];
    const float* W_kv = (const float*)d_in[3];
    const float* ln_g = (const float*)d_in[4];
    const float* ln_b = (const float*)d_in[5];
    const float* W_m1 = (const float*)d_in[6];
    const float* W_m2 = (const float*)d_in[7];
    const float* W_ot = (const float*)d_in[8];
    float* out = (float*)d_out;

    float* ws = (float*)d_ws;
    u16*   qb    = (u16*)ws;
    u16*   h1b   = qb;                                // reuse after attention
    u16*   kvb   = (u16*)(ws + 6553600);
    u16*   m2b   = kvb;                               // reuse after attention
    u16*   catb  = (u16*)(ws + 13107200);
    u16*   ctb   = (u16*)(ws + 19660800);
    u16*   Sb    = (u16*)(ws + 26214400);
    u16*   Pb    = (u16*)(ws + 28311552);
    u16*   Pb12  = (u16*)(ws + 30408704);
    float* Spart = ws + 30511104;                     // att1@0, att2@614400
    float* nq    = ws + 32354304;                     // att0@0,att1@4096,att2@4736
    float* nk    = ws + 32359680;
    float* mu    = ws + 32365056;
    float* rstd  = ws + 32467456;
    u16*   vt0   = (u16*)(ws + 32569856);             // ends 34,208,256
    u16*   vt1   = (u16*)(ws + 34208256);             // ends 35,846,656
    u16*   vt2   = (u16*)(ws + 35846656);             // ends 39,123,456
    u16*   wbt   = (u16*)(ws + 39123456);             // after vt2

    // 0. one-time weight conversion
    k_prep<<<dim3(224), 256, 0, stream>>>(W_in, W_kv, W_m1, W_m2, W_ot, wbt);

    // 1. token GEMMs -> bf16 q/kv
    k_tokens<<<dim3(400, 4, 2), 256, 0, stream>>>(x_hf, x_lf, wbt, qb, kvb);

    // 2. fused V^T + norms
    k_vt_norms<<<dim3(5888, 4), 256, 0, stream>>>(qb, kvb, vt0, vt1, vt2, nq, nk);

    // 3. fused S-GEMMs
    k_sgemm_all<<<dim3(586, 4), 256, 0, stream>>>(qb, kvb, nq, nk, Sb, Spart);

    // 4. fused softmaxes
    k_softmax_all<<<dim3(576, 4), 256, 0, stream>>>(Sb, Pb, Spart, nq, nk, Pb12);

    // 5. fused O-GEMMs + residual (restructured)
    k_ogemm_all<<<dim3(2480, 4), 256, 0, stream>>>(Pb, vt0, Pb12, vt1, vt2, kvb, catb);

    // 6. transpose to token-major + LN stats
    k_transpose_ln<<<dim3(64, 100), 256, 0, stream>>>(catb, ctb, mu, rstd);

    // 7. MLP + out projection
    k_mlp1<<<dim3(1600), 256, 0, stream>>>(ctb, mu, rstd, ln_g, ln_b, wbt, h1b);
    k_mlp2<<<dim3(1600), 256, 0, stream>>>(h1b, ctb, wbt, m2b);
    k_out <<<dim3(1600), 256, 0, stream>>>(m2b, wbt, out);
}

// Round 11
// 330.225 us; speedup vs baseline: 1.0593x; 1.0593x over previous
//
#include <hip/hip_runtime.h>

#define NSP   25600   // 25*32*32 spatial elems per (b, channel)
#define HWC   1024    // 32*32

typedef __attribute__((ext_vector_type(8))) short bf8;   // 8 bf16 = 4 VGPRs
typedef __attribute__((ext_vector_type(4))) float f4;    // MFMA C/D frag
#define MFMA(a,b,c) __builtin_amdgcn_mfma_f32_16x16x32_bf16(a, b, c, 0, 0, 0)
typedef unsigned short u16;

__device__ __forceinline__ u16 f2b(float f) {
    union { float f; unsigned u; } v; v.f = f;
    unsigned r = v.u + 0x7fffu + ((v.u >> 16) & 1u);
    return (u16)(r >> 16);
}
__device__ __forceinline__ float b2f(u16 h) {
    union { unsigned u; float f; } v; v.u = ((unsigned)h) << 16;
    return v.f;
}

// Attention addressing (K re-chunked into 32-contig-elem blocks; legal since
// fold K-order only needs consistency between q/k/v/unfold).
__device__ __forceinline__ long row_base(int att, int b, int m) {
    if (att == 0) { int cc = m >> 5, h = m & 31;   return ((long)(b*128 + cc))*NSP + h*32; }
    else if (att == 1) { int cc = m / 5, u = m - cc*5; return ((long)(b*128 + 32 + cc))*NSP + u*5120; }
    else { int h = m / 5, u = m - h*5;            return ((long)(b*128 + 64))*NSP + u*5120 + h*32; }
}
__device__ __forceinline__ long chunk_off(int att, int kc) {
    if (att == 0) return (long)kc * 1024;
    else if (att == 1) return (long)kc * 32;
    else { int cc = kc / 5, v = kc - cc*5; return (long)cc*NSP + v*1024; }
}

// ---------------- K0: one-time weight convert to bf16 transposed -----------
__global__ __launch_bounds__(256) void k_prep(
        const float* __restrict__ Wi, const float* __restrict__ Wk,
        const float* __restrict__ W1, const float* __restrict__ W2,
        const float* __restrict__ Wo, u16* __restrict__ wbt) {
    int e = blockIdx.x * 256 + threadIdx.x;      // 57344 total
    const float* src; int base, K, N;
    if (e < 8192)       { src = Wi; base = 0;     K = 64;  N = 128; }
    else if (e < 16384) { src = Wk; base = 8192;  K = 64;  N = 128; }
    else if (e < 32768) { src = W1; base = 16384; K = 128; N = 128; }
    else if (e < 49152) { src = W2; base = 32768; K = 128; N = 128; }
    else                { src = Wo; base = 49152; K = 128; N = 64;  }
    int local = e - base, n = local / K, k = local - n * K;
    wbt[e] = f2b(src[k * N + n]);
}

// ---------------- K1: token GEMMs (MFMA) -> bf16 q / kv --------------------
__global__ __launch_bounds__(256) void k_tokens(
        const float* __restrict__ x_hf, const float* __restrict__ x_lf,
        const u16* __restrict__ wbt,
        u16* __restrict__ qb, u16* __restrict__ kvb) {
    // grid (400, 4, 2)
    int s0 = blockIdx.x * 64, b = blockIdx.y, which = blockIdx.z;
    const float* x  = which ? x_lf : x_hf;
    const u16* Wb = wbt + (which ? 8192 : 0);    // [d][c] bf16
    u16* out = which ? kvb : qb;
    __shared__ u16 Axs[64 * 72];   // [token][c]
    __shared__ u16 Wl [128 * 72];  // [d][c]
    int tid = threadIdx.x;
    for (int g = tid; g < 1024; g += 256) {      // W stage: 16B contiguous
        int d = g >> 3, c8 = (g & 7) * 8;
        *(bf8*)&Wl[d * 72 + c8] = *(const bf8*)(Wb + d * 64 + c8);
    }
    for (int g = tid; g < 1024; g += 256) {      // x transpose, packed x4
        int s = g & 63, c4 = (g >> 6) * 4;
        long xb = ((long)(b * 64 + c4)) * NSP + s0 + s;
        ushort4 pk;
        pk.x = f2b(x[xb]);
        pk.y = f2b(x[xb + NSP]);
        pk.z = f2b(x[xb + 2 * NSP]);
        pk.w = f2b(x[xb + 3 * NSP]);
        *(ushort4*)&Axs[s * 72 + c4] = pk;
    }
    __syncthreads();
    int w = tid >> 6, l = tid & 63, quad = l >> 4, col = l & 15;
    f4 z = {0.f, 0.f, 0.f, 0.f};
    f4 acc[8]; for (int i = 0; i < 8; ++i) acc[i] = z;
#pragma unroll
    for (int kc = 0; kc < 2; ++kc) {
        bf8 a = *(bf8*)&Axs[(w * 16 + col) * 72 + kc * 32 + quad * 8];
#pragma unroll
        for (int nt = 0; nt < 8; ++nt) {
            bf8 bb = *(bf8*)&Wl[(nt * 16 + col) * 72 + kc * 32 + quad * 8];
            acc[nt] = MFMA(a, bb, acc[nt]);
        }
    }
#pragma unroll
    for (int nt = 0; nt < 8; ++nt) {
        int d = nt * 16 + col;
        long base = ((long)(b * 128 + d)) * NSP + s0 + w * 16 + quad * 4;
        ushort4 pk;
        pk.x = f2b(acc[nt][0]); pk.y = f2b(acc[nt][1]);
        pk.z = f2b(acc[nt][2]); pk.w = f2b(acc[nt][3]);
        *(ushort4*)(out + base) = pk;
    }
}

// ---------------- K2: fused V^T transposes + L2 norms ----------------------
__global__ __launch_bounds__(256) void k_vt_norms(
        const u16* __restrict__ qb, const u16* __restrict__ kvb,
        u16* __restrict__ vt0, u16* __restrict__ vt1, u16* __restrict__ vt2,
        float* __restrict__ nq, float* __restrict__ nk) {
    // grid (5888, 4): x<3200 -> vt tiles; else norms rows
    int x = blockIdx.x, b = blockIdx.y;
    int tid = threadIdx.x;
    if (x < 3200) {
        int att, kc, pt, P, KC; u16* vt;
        if (x < 800)       { att = 0; kc = x >> 5; pt = (x & 31) * 32; P = 1024; KC = 25;  vt = vt0; }
        else if (x < 1600) { int x2 = x - 800;  att = 1; kc = x2 / 5; pt = (x2 - kc * 5) * 32; P = 160; KC = 160; vt = vt1; }
        else               { int x3 = x - 1600; att = 2; kc = x3 / 5; pt = (x3 - kc * 5) * 32; P = 160; KC = 320; vt = vt2; }
        long co = chunk_off(att, kc);
        __shared__ u16 T[32 * 36];
        {
            int r = tid >> 3, fq = (tid & 7) * 4;
            ushort4 e = *(const ushort4*)(kvb + row_base(att, b, pt + r) + co + fq);
            *(ushort4*)&T[r * 36 + fq] = e;
        }
        __syncthreads();
        {
            int f = tid >> 3, p4 = (tid & 7) * 4;
            ushort4 pk;
            pk.x = T[(p4    ) * 36 + f];
            pk.y = T[(p4 + 1) * 36 + f];
            pk.z = T[(p4 + 2) * 36 + f];
            pk.w = T[(p4 + 3) * 36 + f];
            *(ushort4*)(vt + ((long)b * KC + kc) * 32 * P + (long)f * P + pt + p4) = pk;
        }
    } else {
        int x2 = x - 3200;                       // 0..2687
        int which = x2 >= 1344;
        int xm = which ? x2 - 1344 : x2;
        int att, m, KC, off;
        if (xm < 1024)      { att = 0; m = xm;        KC = 25;  off = b * 1024 + m; }
        else if (xm < 1184) { att = 1; m = xm - 1024; KC = 160; off = 4096 + b * 160 + m; }
        else                { att = 2; m = xm - 1184; KC = 320; off = 4736 + b * 160 + m; }
        const u16* src = which ? kvb : qb;
        float* dst = which ? nk : nq;
        long base = row_base(att, b, m);
        float s = 0.f;
        int K = KC * 32;
        for (int k = tid; k < K; k += 256) {
            float v = b2f(src[base + chunk_off(att, k >> 5) + (k & 31)]);
            s += v * v;
        }
        __shared__ float red[256];
        red[tid] = s; __syncthreads();
        for (int w = 128; w >= 1; w >>= 1) {
            if (tid < w) red[tid] += red[tid + w];
            __syncthreads();
        }
        if (tid == 0) dst[off] = fmaxf(sqrtf(red[0]), 1e-12f);
    }
}

// ---------------- K3: fused S-GEMMs (att0 tiled + att1/2 split-K) ----------
__global__ __launch_bounds__(256) void k_sgemm_all(
        const u16* __restrict__ qb, const u16* __restrict__ kvb,
        const float* __restrict__ nq, const float* __restrict__ nk,
        u16* __restrict__ Sb, float* __restrict__ Spart) {
    // grid (586, 4): x<136 -> att0 triangular 64x64 tile; else split-K
    __shared__ float lds[4096];
    int x = blockIdx.x, b = blockIdx.y;
    int tid = threadIdx.x, w = tid >> 6, l = tid & 63, quad = l >> 4, col = l & 15;
    if (x < 136) {
        u16* Qs = (u16*)lds;          // 64*40
        u16* Ks = Qs + 64 * 40;
        int t = x, i = 0;
        while (t >= (i + 1) * (i + 2) / 2) ++i;
        int j = t - i * (i + 1) / 2;
        int mt = i * 64, nt = j * 64;
        int srow = tid >> 2, g = tid & 3;
        f4 z = {0.f, 0.f, 0.f, 0.f};
        f4 acc[4]; for (int q = 0; q < 4; ++q) acc[q] = z;
        for (int kc = 0; kc < 25; ++kc) {
            long co = (long)kc * 1024;
            {
                int m = mt + srow;
                *(bf8*)&Qs[srow * 40 + g * 8] =
                    *(const bf8*)(qb + ((long)(b*128 + (m >> 5)))*NSP + (m & 31)*32 + co + g*8);
                int n = nt + srow;
                *(bf8*)&Ks[srow * 40 + g * 8] =
                    *(const bf8*)(kvb + ((long)(b*128 + (n >> 5)))*NSP + (n & 31)*32 + co + g*8);
            }
            __syncthreads();
            bf8 a = *(bf8*)&Qs[(w * 16 + col) * 40 + quad * 8];
#pragma unroll
            for (int t2 = 0; t2 < 4; ++t2) {
                bf8 bb = *(bf8*)&Ks[(t2 * 16 + col) * 40 + quad * 8];
                acc[t2] = MFMA(a, bb, acc[t2]);
            }
            __syncthreads();
        }
#pragma unroll
        for (int t2 = 0; t2 < 4; ++t2)
#pragma unroll
            for (int r = 0; r < 4; ++r) {
                int m = mt + w * 16 + quad * 4 + r, n = nt + t2 * 16 + col;
                float v = (n <= m) ? acc[t2][r] / (nq[b*1024 + m] * nk[b*1024 + n]) : 0.f;
                Sb[((long)b * 1024 + m) * 1024 + n] = f2b(v);
            }
    } else {
        int x2 = x - 136;                        // 0..449
        int t = x2 % 15, y = x2 / 15;            // y 0..29
        int att, split, nsplit; float* base;
        if (y < 10) { att = 1; split = y;      nsplit = 10; base = Spart; }
        else        { att = 2; split = y - 10; nsplit = 20; base = Spart + 614400; }
        int i = 0;
        while (t >= (i + 1) * (i + 2) / 2) ++i;
        int j = t - i * (i + 1) / 2;
        int mt = i * 32, nt = j * 32;
        long rm0 = row_base(att, b, mt + col),      rm1 = row_base(att, b, mt + 16 + col);
        long rn0 = row_base(att, b, nt + col),      rn1 = row_base(att, b, nt + 16 + col);
        int ko = quad * 8;
        f4 z = {0.f, 0.f, 0.f, 0.f};
        f4 a00 = z, a01 = z, a10 = z, a11 = z;
#pragma unroll
        for (int s = 0; s < 4; ++s) {
            int kc = split * 16 + w * 4 + s;
            long co = chunk_off(att, kc);
            bf8 qa0 = *(const bf8*)(qb + rm0 + co + ko);
            bf8 qa1 = *(const bf8*)(qb + rm1 + co + ko);
            bf8 kb0 = *(const bf8*)(kvb + rn0 + co + ko);
            bf8 kb1 = *(const bf8*)(kvb + rn1 + co + ko);
            a00 = MFMA(qa0, kb0, a00); a01 = MFMA(qa0, kb1, a01);
            a10 = MFMA(qa1, kb0, a10); a11 = MFMA(qa1, kb1, a11);
        }
        float* my = lds + w * 1024;
#pragma unroll
        for (int r = 0; r < 4; ++r) {
            my[(quad * 4 + r) * 32 + col]            = a00[r];
            my[(quad * 4 + r) * 32 + 16 + col]       = a01[r];
            my[(16 + quad * 4 + r) * 32 + col]       = a10[r];
            my[(16 + quad * 4 + r) * 32 + 16 + col]  = a11[r];
        }
        __syncthreads();
        float* dst = base + ((long)((b * 15 + t) * nsplit + split)) * 1024;
        for (int e = tid; e < 1024; e += 256)
            dst[e] = lds[e] + lds[1024 + e] + lds[2048 + e] + lds[3072 + e];
    }
}

// ---------------- K4: fused softmaxes --------------------------------------
__global__ __launch_bounds__(256) void k_softmax_all(
        const u16* __restrict__ Sb, u16* __restrict__ Pb,
        const float* __restrict__ Spart, const float* __restrict__ nq,
        const float* __restrict__ nk, u16* __restrict__ Pb12) {
    // grid (576, 4): x<256 -> att0 wave-per-row; else att1/2 column softmax
    int xb = blockIdx.x, b = blockIdx.y, tid = threadIdx.x;
    if (xb < 256) {
        int w = tid >> 6, lane = tid & 63;
        int m = xb * 4 + w;
        const u16* row = Sb + ((long)b * 1024 + m) * 1024;
        u16* pr = Pb + ((long)b * 1024 + m) * 1024;
        int e0 = lane * 16;
        bf8 x0 = *(const bf8*)(row + e0);
        bf8 x1 = *(const bf8*)(row + e0 + 8);
        float v[16];
#pragma unroll
        for (int j = 0; j < 8; ++j) { v[j] = b2f(((u16*)&x0)[j]); v[8 + j] = b2f(((u16*)&x1)[j]); }
        float mx = -1e30f;
#pragma unroll
        for (int j = 0; j < 16; ++j) if (e0 + j <= m) mx = fmaxf(mx, v[j]);
#pragma unroll
        for (int o = 32; o >= 1; o >>= 1) mx = fmaxf(mx, __shfl_xor(mx, o));
        float s = 0.f;
#pragma unroll
        for (int j = 0; j < 16; ++j) {
            float e = (e0 + j <= m) ? __expf(v[j] - mx) : 0.f;
            v[j] = e; s += e;
        }
#pragma unroll
        for (int o = 32; o >= 1; o >>= 1) s += __shfl_xor(s, o);
        float inv = 1.f / s;
        bf8 o0, o1;
#pragma unroll
        for (int j = 0; j < 8; ++j) {
            ((u16*)&o0)[j] = f2b(v[j] * inv);
            ((u16*)&o1)[j] = f2b(v[8 + j] * inv);
        }
        *(bf8*)(pr + e0) = o0;
        *(bf8*)(pr + e0 + 8) = o1;
    } else {
        int x = xb - 256;                        // 0..319
        int att = (x < 160) ? 1 : 2;
        int m = (att == 1) ? x : x - 160;
        int nsplit = (att == 1) ? 10 : 20;
        const float* base = (att == 1) ? Spart : Spart + 614400;
        int noff = (att == 1) ? 4096 : 4736;
        u16* P = Pb12 + ((att == 1) ? 0 : 102400);
        int i = m >> 5, ro = (m & 31) * 32;
        int n = tid;
        bool act = (n <= m) && (n < 160);
        float myv = 0.f;
        if (act) {
            int t = i * (i + 1) / 2 + (n >> 5);
            const float* src = base + ((long)((b * 15 + t) * nsplit)) * 1024 + ro + (n & 31);
            float s = 0.f;
            for (int sp = 0; sp < nsplit; ++sp) s += src[(long)sp * 1024];
            myv = s / (nq[noff + b * 160 + m] * nk[noff + b * 160 + n]);
        }
        __shared__ float red[256];
        red[tid] = act ? myv : -1e30f; __syncthreads();
        for (int w = 128; w >= 1; w >>= 1) {
            if (tid < w) red[tid] = fmaxf(red[tid], red[tid + w]);
            __syncthreads();
        }
        float mx = red[0]; __syncthreads();
        float e = act ? __expf(myv - mx) : 0.f;
        red[tid] = e; __syncthreads();
        for (int w = 128; w >= 1; w >>= 1) {
            if (tid < w) red[tid] += red[tid + w];
            __syncthreads();
        }
        float inv = 1.f / red[0];
        if (n < 160) P[((long)b * 160 + m) * 160 + n] = f2b(e * inv);
    }
}

// ---------------- K5: fused O-GEMMs + residual (R9 shape, 64-p slab) -------
// att0: R9 block shape (64 m x 32 f, one kc) but stage 64-wide p-slab per
// barrier round -> 4 MFMA/wave/round, half the barriers of R9.
// att1/2: R9's per-chunk loop (small LDS footprint preserved).
__global__ __launch_bounds__(256) void k_ogemm_all(
        const u16* __restrict__ Pb, const u16* __restrict__ vt0,
        const u16* __restrict__ Pb12, const u16* __restrict__ vt1,
        const u16* __restrict__ vt2, const u16* __restrict__ kvb,
        u16* __restrict__ catb) {
    // grid (2800, 4): x<400 -> att0; else att1/2
    __shared__ u16 lds[64 * 72 + 32 * 72];   // 13,824 B
    int x = blockIdx.x, b = blockIdx.y;
    int tid = threadIdx.x, w = tid >> 6, l = tid & 63, quad = l >> 4, col = l & 15;
    if (x < 400) {
        int mtt = x & 15, kc = x >> 4;
        int mt = mtt * 64;
        long co = (long)kc * 1024;
        const u16* vtc = vt0 + ((long)b * 25 + kc) * 32 * 1024;
        u16* Ps = lds;              // 64 x 72 (rows m-local, cols p-slab 64)
        u16* Vs = lds + 64 * 72;    // 32 x 72 (rows f-local, cols p-slab 64)
        f4 z = {0.f, 0.f, 0.f, 0.f};
        f4 acc[2]; acc[0] = z; acc[1] = z;
        for (int s = 0; s <= mtt; ++s) {         // p = 0 .. mt+64 (P zero past m)
            int p0 = s * 64;
#pragma unroll
            for (int i = 0; i < 2; ++i) {        // P stage: 64 x 64
                int idx = i * 256 + tid;
                int row = idx >> 3, c8 = (idx & 7) * 8;
                *(bf8*)&Ps[row * 72 + c8] =
                    *(const bf8*)(Pb + ((long)(b * 1024 + mt + row)) * 1024 + p0 + c8);
            }
            {                                    // V stage: 32 x 64
                int f = tid >> 3, p8 = (tid & 7) * 8;
                *(bf8*)&Vs[f * 72 + p8] =
                    *(const bf8*)(vtc + (long)f * 1024 + p0 + p8);
            }
            __syncthreads();
            bf8 a0 = *(bf8*)&Ps[(w * 16 + col) * 72 + quad * 8];
            bf8 a1 = *(bf8*)&Ps[(w * 16 + col) * 72 + 32 + quad * 8];
#pragma unroll
            for (int t2 = 0; t2 < 2; ++t2) {
                bf8 b0 = *(bf8*)&Vs[(t2 * 16 + col) * 72 + quad * 8];
                bf8 b1 = *(bf8*)&Vs[(t2 * 16 + col) * 72 + 32 + quad * 8];
                acc[t2] = MFMA(a0, b0, acc[t2]);
                acc[t2] = MFMA(a1, b1, acc[t2]);
            }
            __syncthreads();
        }
#pragma unroll
        for (int t2 = 0; t2 < 2; ++t2)
#pragma unroll
            for (int r = 0; r < 4; ++r) {
                int m = mt + w * 16 + quad * 4 + r, f = t2 * 16 + col;
                long adr = ((long)(b * 128 + (m >> 5))) * NSP + (m & 31) * 32 + co + f;
                catb[adr] = f2b(acc[t2][r] + b2f(kvb[adr]));
            }
    } else {
        int x2 = x - 400;                        // 0..2399
        int it = x2 % 5, y = x2 / 5;             // y 0..479
        int att, kc, KC; const u16 *vt, *P;
        if (y < 160) { att = 1; kc = y;       KC = 160; vt = vt1; P = Pb12; }
        else         { att = 2; kc = y - 160; KC = 320; vt = vt2; P = Pb12 + 102400; }
        int mt = it * 32;
        const u16* vtc = vt + ((long)b * KC + kc) * 32 * 160;
        u16* Ps = lds;                 // 32*40
        u16* Vs = lds + 32 * 40;       // 32*40
        int mh = w & 1, fh = w >> 1;
        f4 acc = {0.f, 0.f, 0.f, 0.f};
        for (int nt2 = 0; nt2 <= it; ++nt2) {
            {
                int row = tid >> 3, g4 = (tid & 7) * 4;
                *(ushort4*)&Ps[row * 40 + g4] =
                    *(const ushort4*)(P + ((long)(b * 160 + mt + row)) * 160 + nt2 * 32 + g4);
                *(ushort4*)&Vs[row * 40 + g4] =
                    *(const ushort4*)(vtc + (long)row * 160 + nt2 * 32 + g4);
            }
            __syncthreads();
            bf8 a  = *(bf8*)&Ps[(mh * 16 + col) * 40 + quad * 8];
            bf8 bb = *(bf8*)&Vs[(fh * 16 + col) * 40 + quad * 8];
            acc = MFMA(a, bb, acc);
            __syncthreads();
        }
#pragma unroll
        for (int r = 0; r < 4; ++r) {
            int m = mt + mh * 16 + quad * 4 + r, f = fh * 16 + col;
            long adr = row_base(att, b, m) + chunk_off(att, kc) + f;
            catb[adr] = f2b(acc[r] + b2f(kvb[adr]));
        }
    }
}

// ---------------- K6: transpose cat -> ct + fused LN stats -----------------
__global__ __launch_bounds__(256) void k_transpose_ln(
        const u16* __restrict__ catb, u16* __restrict__ ctb,
        float* __restrict__ mu, float* __restrict__ rstd) {
    // grid (64, 100): 16 tokens (hw) x 128 d per block
    int hwt = blockIdx.x * 16, bn = blockIdx.y;
    int b = bn / 25, uv = bn - b * 25;
    __shared__ u16 T[16 * 136];
    int tid = threadIdx.x;
    const u16* src = catb + (long)b * 128 * NSP + (long)uv * HWC + hwt;
    {
        int d = tid >> 1, hw8 = (tid & 1) * 8;
        bf8 v = *(const bf8*)(src + (long)d * NSP + hw8);
#pragma unroll
        for (int j = 0; j < 8; ++j) T[(hw8 + j) * 136 + d] = ((u16*)&v)[j];
    }
    __syncthreads();
    {
        int w = tid >> 6, l = tid & 63;
        int tk = w * 4 + (l >> 4), dg = (l & 15) * 8;
        bf8 vv = *(bf8*)&T[tk * 136 + dg];
        float s = 0.f, s2 = 0.f;
#pragma unroll
        for (int j = 0; j < 8; ++j) {
            float f = b2f(((u16*)&vv)[j]); s += f; s2 += f * f;
        }
        for (int o = 8; o >= 1; o >>= 1) { s += __shfl_xor(s, o); s2 += __shfl_xor(s2, o); }
        if ((l & 15) == 0) {
            int t = bn * 1024 + hwt + tk;
            float m = s * (1.f / 128.f);
            float var = s2 * (1.f / 128.f) - m * m;
            mu[t] = m; rstd[t] = rsqrtf(var + 1e-5f);
        }
    }
    {
        int hw = tid >> 4, d8 = (tid & 15) * 8;
        *(bf8*)(ctb + ((long)(bn * 1024 + hwt + hw)) * 128 + d8) = *(bf8*)&T[hw * 136 + d8];
    }
}

// ---------------- K8: h1 = relu(LN(ct) @ W1) (MFMA) ------------------------
__global__ __launch_bounds__(256) void k_mlp1(
        const u16* __restrict__ ctb, const float* __restrict__ mu,
        const float* __restrict__ rstd, const float* __restrict__ g,
        const float* __restrict__ be, const u16* __restrict__ wbt,
        u16* __restrict__ h1b) {
    int tt = blockIdx.x * 64, tid = threadIdx.x;
    const u16* W1b = wbt + 16384;                // [n][k] 128x128
    __shared__ u16 As[64 * 136], Wt[128 * 136];
    __shared__ float gl[128], bl[128];
    if (tid < 128) { gl[tid] = g[tid]; bl[tid] = be[tid]; }
    for (int q = tid; q < 2048; q += 256) {      // W stage: 16B contiguous
        int n = q >> 4, k8 = (q & 15) * 8;
        *(bf8*)&Wt[n * 136 + k8] = *(const bf8*)(W1b + n * 128 + k8);
    }
    __syncthreads();                             // gl/bl visible
    for (int q = tid; q < 1024; q += 256) {      // A: LN transform, bf8
        int row = q >> 4, k8 = (q & 15) * 8, t = tt + row;
        bf8 cv = *(const bf8*)(ctb + (long)t * 128 + k8);
        float m = mu[t], rs = rstd[t];
        bf8 av;
#pragma unroll
        for (int j = 0; j < 8; ++j)
            ((u16*)&av)[j] = f2b((b2f(((u16*)&cv)[j]) - m) * rs * gl[k8 + j] + bl[k8 + j]);
        *(bf8*)&As[row * 136 + k8] = av;
    }
    __syncthreads();
    int w = tid >> 6, l = tid & 63, quad = l >> 4, col = l & 15;
    f4 z = {0.f, 0.f, 0.f, 0.f};
    f4 acc[8]; for (int i = 0; i < 8; ++i) acc[i] = z;
#pragma unroll
    for (int kc = 0; kc < 4; ++kc) {
        bf8 a = *(bf8*)&As[(w * 16 + col) * 136 + kc * 32 + quad * 8];
#pragma unroll
        for (int nt = 0; nt < 8; ++nt) {
            bf8 bb = *(bf8*)&Wt[(nt * 16 + col) * 136 + kc * 32 + quad * 8];
            acc[nt] = MFMA(a, bb, acc[nt]);
        }
    }
#pragma unroll
    for (int nt = 0; nt < 8; ++nt)
#pragma unroll
        for (int r = 0; r < 4; ++r) {
            int t = tt + w * 16 + quad * 4 + r, n = nt * 16 + col;
            h1b[(long)t * 128 + n] = f2b(fmaxf(acc[nt][r], 0.f));
        }
}

// ---------------- K9: m2 = h1 @ W2 + ct (MFMA) -----------------------------
__global__ __launch_bounds__(256) void k_mlp2(
        const u16* __restrict__ h1b, const u16* __restrict__ ctb,
        const u16* __restrict__ wbt, u16* __restrict__ m2b) {
    int tt = blockIdx.x * 64, tid = threadIdx.x;
    const u16* W2b = wbt + 32768;                // [n][k] 128x128
    __shared__ u16 As[64 * 136], Wt[128 * 136];
    for (int q = tid; q < 2048; q += 256) {
        int n = q >> 4, k8 = (q & 15) * 8;
        *(bf8*)&Wt[n * 136 + k8] = *(const bf8*)(W2b + n * 128 + k8);
    }
    for (int q = tid; q < 1024; q += 256) {
        int row = q >> 4, k8 = (q & 15) * 8;
        *(bf8*)&As[row * 136 + k8] = *(const bf8*)(h1b + (long)(tt + row) * 128 + k8);
    }
    __syncthreads();
    int w = tid >> 6, l = tid & 63, quad = l >> 4, col = l & 15;
    f4 z = {0.f, 0.f, 0.f, 0.f};
    f4 acc[8]; for (int i = 0; i < 8; ++i) acc[i] = z;
#pragma unroll
    for (int kc = 0; kc < 4; ++kc) {
        bf8 a = *(bf8*)&As[(w * 16 + col) * 136 + kc * 32 + quad * 8];
#pragma unroll
        for (int nt = 0; nt < 8; ++nt) {
            bf8 bb = *(bf8*)&Wt[(nt * 16 + col) * 136 + kc * 32 + quad * 8];
            acc[nt] = MFMA(a, bb, acc[nt]);
        }
    }
#pragma unroll
    for (int nt = 0; nt < 8; ++nt)
#pragma unroll
        for (int r = 0; r < 4; ++r) {
            int t = tt + w * 16 + quad * 4 + r, n = nt * 16 + col;
            m2b[(long)t * 128 + n] = f2b(acc[nt][r] + b2f(ctb[(long)t * 128 + n]));
        }
}

// ---------------- K10: out = m2 @ W_out (MFMA), scatter --------------------
__global__ __launch_bounds__(256) void k_out(
        const u16* __restrict__ m2b, const u16* __restrict__ wbt,
        float* __restrict__ out) {
    int tt = blockIdx.x * 64, tid = threadIdx.x;
    const u16* Wob = wbt + 49152;                // [o][k] 64x128
    __shared__ u16 As[64 * 136], Wt[64 * 136];
    for (int q = tid; q < 1024; q += 256) {
        int o = q >> 4, k8 = (q & 15) * 8;
        *(bf8*)&Wt[o * 136 + k8] = *(const bf8*)(Wob + o * 128 + k8);
    }
    for (int q = tid; q < 1024; q += 256) {
        int row = q >> 4, k8 = (q & 15) * 8;
        *(bf8*)&As[row * 136 + k8] = *(const bf8*)(m2b + (long)(tt + row) * 128 + k8);
    }
    __syncthreads();
    int w = tid >> 6, l = tid & 63, quad = l >> 4, col = l & 15;
    f4 z = {0.f, 0.f, 0.f, 0.f};
    f4 acc[4]; for (int i = 0; i < 4; ++i) acc[i] = z;
#pragma unroll
    for (int kc = 0; kc < 4; ++kc) {
        bf8 a = *(bf8*)&As[(w * 16 + col) * 136 + kc * 32 + quad * 8];
#pragma unroll
        for (int nt = 0; nt < 4; ++nt) {
            bf8 bb = *(bf8*)&Wt[(nt * 16 + col) * 136 + kc * 32 + quad * 8];
            acc[nt] = MFMA(a, bb, acc[nt]);
        }
    }
    int t0 = tt + w * 16 + quad * 4;
    int bn = t0 >> 10, hw = t0 & 1023;
    int b = bn / 25, uv = bn - b * 25;
#pragma unroll
    for (int nt = 0; nt < 4; ++nt) {
        int o = nt * 16 + col;
        float4 pk = {acc[nt][0], acc[nt][1], acc[nt][2], acc[nt][3]};
        *(float4*)(out + ((long)((b * 64 + o) * 25 + uv)) * 1024 + hw) = pk;
    }
}

// ---------------- launch ---------------------------------------------------
extern "C" void kernel_launch(void* const* d_in, const int* in_sizes, int n_in,
                              void* d_out, int out_size, void* d_ws, size_t ws_size,
                              hipStream_t stream) {
    const float* x_lf = (const float*)d_in[0];
    const float* x_hf = (const float*)d_in[1];
    const float* W_in = (const float*)d_in[2];
    const float* W_kv = (const float*)d_in[3];
    const float* ln_g = (const float*)d_in[4];
    const float* ln_b = (const float*)d_in[5];
    const float* W_m1 = (const float*)d_in[6];
    const float* W_m2 = (const float*)d_in[7];
    const float* W_ot = (const float*)d_in[8];
    float* out = (float*)d_out;

    float* ws = (float*)d_ws;
    u16*   qb    = (u16*)ws;
    u16*   h1b   = qb;                                // reuse after attention
    u16*   kvb   = (u16*)(ws + 6553600);
    u16*   m2b   = kvb;                               // reuse after attention
    u16*   catb  = (u16*)(ws + 13107200);
    u16*   ctb   = (u16*)(ws + 19660800);
    u16*   Sb    = (u16*)(ws + 26214400);
    u16*   Pb    = (u16*)(ws + 28311552);
    u16*   Pb12  = (u16*)(ws + 30408704);
    float* Spart = ws + 30511104;                     // att1@0, att2@614400
    float* nq    = ws + 32354304;                     // att0@0,att1@4096,att2@4736
    float* nk    = ws + 32359680;
    float* mu    = ws + 32365056;
    float* rstd  = ws + 32467456;
    u16*   vt0   = (u16*)(ws + 32569856);             // ends 34,208,256
    u16*   vt1   = (u16*)(ws + 34208256);             // ends 35,846,656
    u16*   vt2   = (u16*)(ws + 35846656);             // ends 39,123,456
    u16*   wbt   = (u16*)(ws + 39123456);             // after vt2

    // 0. one-time weight conversion
    k_prep<<<dim3(224), 256, 0, stream>>>(W_in, W_kv, W_m1, W_m2, W_ot, wbt);

    // 1. token GEMMs -> bf16 q/kv
    k_tokens<<<dim3(400, 4, 2), 256, 0, stream>>>(x_hf, x_lf, wbt, qb, kvb);

    // 2. fused V^T + norms
    k_vt_norms<<<dim3(5888, 4), 256, 0, stream>>>(qb, kvb, vt0, vt1, vt2, nq, nk);

    // 3. fused S-GEMMs
    k_sgemm_all<<<dim3(586, 4), 256, 0, stream>>>(qb, kvb, nq, nk, Sb, Spart);

    // 4. fused softmaxes
    k_softmax_all<<<dim3(576, 4), 256, 0, stream>>>(Sb, Pb, Spart, nq, nk, Pb12);

    // 5. fused O-GEMMs + residual (R9 shape + 64-p slab)
    k_ogemm_all<<<dim3(2800, 4), 256, 0, stream>>>(Pb, vt0, Pb12, vt1, vt2, kvb, catb);

    // 6. transpose to token-major + LN stats
    k_transpose_ln<<<dim3(64, 100), 256, 0, stream>>>(catb, ctb, mu, rstd);

    // 7. MLP + out projection
    k_mlp1<<<dim3(1600), 256, 0, stream>>>(ctb, mu, rstd, ln_g, ln_b, wbt, h1b);
    k_mlp2<<<dim3(1600), 256, 0, stream>>>(h1b, ctb, wbt, m2b);
    k_out <<<dim3(1600), 256, 0, stream>>>(m2b, wbt, out);
}

// Round 12
// 309.136 us; speedup vs baseline: 1.1315x; 1.0682x over previous
//
#include <hip/hip_runtime.h>

#define NSP   25600   // 25*32*32 spatial elems per (b, channel)
#define HWC   1024    // 32*32

typedef __attribute__((ext_vector_type(8))) short bf8;   // 8 bf16 = 4 VGPRs
typedef __attribute__((ext_vector_type(4))) float f4;    // MFMA C/D frag
#define MFMA(a,b,c) __builtin_amdgcn_mfma_f32_16x16x32_bf16(a, b, c, 0, 0, 0)
typedef unsigned short u16;

__device__ __forceinline__ u16 f2b(float f) {
    union { float f; unsigned u; } v; v.f = f;
    unsigned r = v.u + 0x7fffu + ((v.u >> 16) & 1u);
    return (u16)(r >> 16);
}
__device__ __forceinline__ float b2f(u16 h) {
    union { unsigned u; float f; } v; v.u = ((unsigned)h) << 16;
    return v.f;
}

// Attention addressing (K re-chunked into 32-contig-elem blocks; legal since
// fold K-order only needs consistency between q/k/v/unfold).
__device__ __forceinline__ long row_base(int att, int b, int m) {
    if (att == 0) { int cc = m >> 5, h = m & 31;   return ((long)(b*128 + cc))*NSP + h*32; }
    else if (att == 1) { int cc = m / 5, u = m - cc*5; return ((long)(b*128 + 32 + cc))*NSP + u*5120; }
    else { int h = m / 5, u = m - h*5;            return ((long)(b*128 + 64))*NSP + u*5120 + h*32; }
}
__device__ __forceinline__ long chunk_off(int att, int kc) {
    if (att == 0) return (long)kc * 1024;
    else if (att == 1) return (long)kc * 32;
    else { int cc = kc / 5, v = kc - cc*5; return (long)cc*NSP + v*1024; }
}

// ---------------- K0: one-time weight convert to bf16 transposed -----------
__global__ __launch_bounds__(256) void k_prep(
        const float* __restrict__ Wi, const float* __restrict__ Wk,
        const float* __restrict__ W1, const float* __restrict__ W2,
        const float* __restrict__ Wo, u16* __restrict__ wbt) {
    int e = blockIdx.x * 256 + threadIdx.x;      // 57344 total
    const float* src; int base, K, N;
    if (e < 8192)       { src = Wi; base = 0;     K = 64;  N = 128; }
    else if (e < 16384) { src = Wk; base = 8192;  K = 64;  N = 128; }
    else if (e < 32768) { src = W1; base = 16384; K = 128; N = 128; }
    else if (e < 49152) { src = W2; base = 32768; K = 128; N = 128; }
    else                { src = Wo; base = 49152; K = 128; N = 64;  }
    int local = e - base, n = local / K, k = local - n * K;
    wbt[e] = f2b(src[k * N + n]);
}

// ---------------- K1: token GEMMs (MFMA) -> bf16 q / kv --------------------
__global__ __launch_bounds__(256) void k_tokens(
        const float* __restrict__ x_hf, const float* __restrict__ x_lf,
        const u16* __restrict__ wbt,
        u16* __restrict__ qb, u16* __restrict__ kvb) {
    // grid (400, 4, 2)
    int s0 = blockIdx.x * 64, b = blockIdx.y, which = blockIdx.z;
    const float* x  = which ? x_lf : x_hf;
    const u16* Wb = wbt + (which ? 8192 : 0);    // [d][c] bf16
    u16* out = which ? kvb : qb;
    __shared__ u16 Axs[64 * 72];   // [token][c]
    __shared__ u16 Wl [128 * 72];  // [d][c]
    int tid = threadIdx.x;
    for (int g = tid; g < 1024; g += 256) {      // W stage: 16B contiguous
        int d = g >> 3, c8 = (g & 7) * 8;
        *(bf8*)&Wl[d * 72 + c8] = *(const bf8*)(Wb + d * 64 + c8);
    }
    for (int g = tid; g < 1024; g += 256) {      // x transpose, packed x4
        int s = g & 63, c4 = (g >> 6) * 4;
        long xb = ((long)(b * 64 + c4)) * NSP + s0 + s;
        ushort4 pk;
        pk.x = f2b(x[xb]);
        pk.y = f2b(x[xb + NSP]);
        pk.z = f2b(x[xb + 2 * NSP]);
        pk.w = f2b(x[xb + 3 * NSP]);
        *(ushort4*)&Axs[s * 72 + c4] = pk;
    }
    __syncthreads();
    int w = tid >> 6, l = tid & 63, quad = l >> 4, col = l & 15;
    f4 z = {0.f, 0.f, 0.f, 0.f};
    f4 acc[8]; for (int i = 0; i < 8; ++i) acc[i] = z;
#pragma unroll
    for (int kc = 0; kc < 2; ++kc) {
        bf8 a = *(bf8*)&Axs[(w * 16 + col) * 72 + kc * 32 + quad * 8];
#pragma unroll
        for (int nt = 0; nt < 8; ++nt) {
            bf8 bb = *(bf8*)&Wl[(nt * 16 + col) * 72 + kc * 32 + quad * 8];
            acc[nt] = MFMA(a, bb, acc[nt]);
        }
    }
#pragma unroll
    for (int nt = 0; nt < 8; ++nt) {
        int d = nt * 16 + col;
        long base = ((long)(b * 128 + d)) * NSP + s0 + w * 16 + quad * 4;
        ushort4 pk;
        pk.x = f2b(acc[nt][0]); pk.y = f2b(acc[nt][1]);
        pk.z = f2b(acc[nt][2]); pk.w = f2b(acc[nt][3]);
        *(ushort4*)(out + base) = pk;
    }
}

// ---------------- K2: fused V^T transposes + L2 norms (wave-per-row) -------
__global__ __launch_bounds__(256) void k_vt_norms(
        const u16* __restrict__ qb, const u16* __restrict__ kvb,
        u16* __restrict__ vt0, u16* __restrict__ vt1, u16* __restrict__ vt2,
        float* __restrict__ nq, float* __restrict__ nk) {
    // grid (3872, 4): x<3200 -> vt tiles; else norms (wave-per-row, bf8 loads)
    int x = blockIdx.x, b = blockIdx.y;
    int tid = threadIdx.x;
    if (x < 3200) {
        int att, kc, pt, P, KC; u16* vt;
        if (x < 800)       { att = 0; kc = x >> 5; pt = (x & 31) * 32; P = 1024; KC = 25;  vt = vt0; }
        else if (x < 1600) { int x2 = x - 800;  att = 1; kc = x2 / 5; pt = (x2 - kc * 5) * 32; P = 160; KC = 160; vt = vt1; }
        else               { int x3 = x - 1600; att = 2; kc = x3 / 5; pt = (x3 - kc * 5) * 32; P = 160; KC = 320; vt = vt2; }
        long co = chunk_off(att, kc);
        __shared__ u16 T[32 * 36];
        {
            int r = tid >> 3, fq = (tid & 7) * 4;
            ushort4 e = *(const ushort4*)(kvb + row_base(att, b, pt + r) + co + fq);
            *(ushort4*)&T[r * 36 + fq] = e;
        }
        __syncthreads();
        {
            int f = tid >> 3, p4 = (tid & 7) * 4;
            ushort4 pk;
            pk.x = T[(p4    ) * 36 + f];
            pk.y = T[(p4 + 1) * 36 + f];
            pk.z = T[(p4 + 2) * 36 + f];
            pk.w = T[(p4 + 3) * 36 + f];
            *(ushort4*)(vt + ((long)b * KC + kc) * 32 * P + (long)f * P + pt + p4) = pk;
        }
    } else {
        int x2 = x - 3200;                       // 0..671
        int which = x2 >= 336;
        int g = which ? x2 - 336 : x2;           // 0..335
        int att, m0, KC;
        if (g < 256)      { att = 0; m0 = g * 4;         KC = 25;  }
        else if (g < 296) { att = 1; m0 = (g - 256) * 4; KC = 160; }
        else              { att = 2; m0 = (g - 296) * 4; KC = 320; }
        const u16* src = which ? kvb : qb;
        float* dst = which ? nk : nq;
        int w = tid >> 6, lane = tid & 63;
        int m = m0 + w;
        long base = row_base(att, b, m);
        int K = KC * 32;
        float s = 0.f;
        for (int k8 = lane * 8; k8 < K; k8 += 512) {
            bf8 v = *(const bf8*)(src + base + chunk_off(att, k8 >> 5) + (k8 & 31));
#pragma unroll
            for (int j = 0; j < 8; ++j) { float f = b2f(((u16*)&v)[j]); s += f * f; }
        }
        for (int o = 32; o >= 1; o >>= 1) s += __shfl_xor(s, o);
        if (lane == 0) {
            int off = (att == 0) ? b * 1024 + m
                                 : ((att == 1) ? 4096 : 4736) + b * 160 + m;
            dst[off] = fmaxf(sqrtf(s), 1e-12f);
        }
    }
}

// ---------------- K3: fused S-GEMMs (att0 tiled + att1/2 split-K) ----------
__global__ __launch_bounds__(256) void k_sgemm_all(
        const u16* __restrict__ qb, const u16* __restrict__ kvb,
        const float* __restrict__ nq, const float* __restrict__ nk,
        u16* __restrict__ Sb, float* __restrict__ Spart) {
    // grid (586, 4): x<136 -> att0 triangular 64x64 tile; else split-K
    __shared__ float lds[4096];
    int x = blockIdx.x, b = blockIdx.y;
    int tid = threadIdx.x, w = tid >> 6, l = tid & 63, quad = l >> 4, col = l & 15;
    if (x < 136) {
        u16* Qs = (u16*)lds;          // 64*40
        u16* Ks = Qs + 64 * 40;
        int t = x, i = 0;
        while (t >= (i + 1) * (i + 2) / 2) ++i;
        int j = t - i * (i + 1) / 2;
        int mt = i * 64, nt = j * 64;
        int srow = tid >> 2, g = tid & 3;
        f4 z = {0.f, 0.f, 0.f, 0.f};
        f4 acc[4]; for (int q = 0; q < 4; ++q) acc[q] = z;
        for (int kc = 0; kc < 25; ++kc) {
            long co = (long)kc * 1024;
            {
                int m = mt + srow;
                *(bf8*)&Qs[srow * 40 + g * 8] =
                    *(const bf8*)(qb + ((long)(b*128 + (m >> 5)))*NSP + (m & 31)*32 + co + g*8);
                int n = nt + srow;
                *(bf8*)&Ks[srow * 40 + g * 8] =
                    *(const bf8*)(kvb + ((long)(b*128 + (n >> 5)))*NSP + (n & 31)*32 + co + g*8);
            }
            __syncthreads();
            bf8 a = *(bf8*)&Qs[(w * 16 + col) * 40 + quad * 8];
#pragma unroll
            for (int t2 = 0; t2 < 4; ++t2) {
                bf8 bb = *(bf8*)&Ks[(t2 * 16 + col) * 40 + quad * 8];
                acc[t2] = MFMA(a, bb, acc[t2]);
            }
            __syncthreads();
        }
#pragma unroll
        for (int t2 = 0; t2 < 4; ++t2)
#pragma unroll
            for (int r = 0; r < 4; ++r) {
                int m = mt + w * 16 + quad * 4 + r, n = nt + t2 * 16 + col;
                float v = (n <= m) ? acc[t2][r] / (nq[b*1024 + m] * nk[b*1024 + n]) : 0.f;
                Sb[((long)b * 1024 + m) * 1024 + n] = f2b(v);
            }
    } else {
        int x2 = x - 136;                        // 0..449
        int t = x2 % 15, y = x2 / 15;            // y 0..29
        int att, split, nsplit; float* base;
        if (y < 10) { att = 1; split = y;      nsplit = 10; base = Spart; }
        else        { att = 2; split = y - 10; nsplit = 20; base = Spart + 614400; }
        int i = 0;
        while (t >= (i + 1) * (i + 2) / 2) ++i;
        int j = t - i * (i + 1) / 2;
        int mt = i * 32, nt = j * 32;
        long rm0 = row_base(att, b, mt + col),      rm1 = row_base(att, b, mt + 16 + col);
        long rn0 = row_base(att, b, nt + col),      rn1 = row_base(att, b, nt + 16 + col);
        int ko = quad * 8;
        f4 z = {0.f, 0.f, 0.f, 0.f};
        f4 a00 = z, a01 = z, a10 = z, a11 = z;
#pragma unroll
        for (int s = 0; s < 4; ++s) {
            int kc = split * 16 + w * 4 + s;
            long co = chunk_off(att, kc);
            bf8 qa0 = *(const bf8*)(qb + rm0 + co + ko);
            bf8 qa1 = *(const bf8*)(qb + rm1 + co + ko);
            bf8 kb0 = *(const bf8*)(kvb + rn0 + co + ko);
            bf8 kb1 = *(const bf8*)(kvb + rn1 + co + ko);
            a00 = MFMA(qa0, kb0, a00); a01 = MFMA(qa0, kb1, a01);
            a10 = MFMA(qa1, kb0, a10); a11 = MFMA(qa1, kb1, a11);
        }
        float* my = lds + w * 1024;
#pragma unroll
        for (int r = 0; r < 4; ++r) {
            my[(quad * 4 + r) * 32 + col]            = a00[r];
            my[(quad * 4 + r) * 32 + 16 + col]       = a01[r];
            my[(16 + quad * 4 + r) * 32 + col]       = a10[r];
            my[(16 + quad * 4 + r) * 32 + 16 + col]  = a11[r];
        }
        __syncthreads();
        float* dst = base + ((long)((b * 15 + t) * nsplit + split)) * 1024;
        for (int e = tid; e < 1024; e += 256)
            dst[e] = lds[e] + lds[1024 + e] + lds[2048 + e] + lds[3072 + e];
    }
}

// ---------------- K4: fused softmaxes --------------------------------------
__global__ __launch_bounds__(256) void k_softmax_all(
        const u16* __restrict__ Sb, u16* __restrict__ Pb,
        const float* __restrict__ Spart, const float* __restrict__ nq,
        const float* __restrict__ nk, u16* __restrict__ Pb12) {
    // grid (576, 4): x<256 -> att0 wave-per-row; else att1/2 column softmax
    int xb = blockIdx.x, b = blockIdx.y, tid = threadIdx.x;
    if (xb < 256) {
        int w = tid >> 6, lane = tid & 63;
        int m = xb * 4 + w;
        const u16* row = Sb + ((long)b * 1024 + m) * 1024;
        u16* pr = Pb + ((long)b * 1024 + m) * 1024;
        int e0 = lane * 16;
        bf8 x0 = *(const bf8*)(row + e0);
        bf8 x1 = *(const bf8*)(row + e0 + 8);
        float v[16];
#pragma unroll
        for (int j = 0; j < 8; ++j) { v[j] = b2f(((u16*)&x0)[j]); v[8 + j] = b2f(((u16*)&x1)[j]); }
        float mx = -1e30f;
#pragma unroll
        for (int j = 0; j < 16; ++j) if (e0 + j <= m) mx = fmaxf(mx, v[j]);
#pragma unroll
        for (int o = 32; o >= 1; o >>= 1) mx = fmaxf(mx, __shfl_xor(mx, o));
        float s = 0.f;
#pragma unroll
        for (int j = 0; j < 16; ++j) {
            float e = (e0 + j <= m) ? __expf(v[j] - mx) : 0.f;
            v[j] = e; s += e;
        }
#pragma unroll
        for (int o = 32; o >= 1; o >>= 1) s += __shfl_xor(s, o);
        float inv = 1.f / s;
        bf8 o0, o1;
#pragma unroll
        for (int j = 0; j < 8; ++j) {
            ((u16*)&o0)[j] = f2b(v[j] * inv);
            ((u16*)&o1)[j] = f2b(v[8 + j] * inv);
        }
        *(bf8*)(pr + e0) = o0;
        *(bf8*)(pr + e0 + 8) = o1;
    } else {
        int x = xb - 256;                        // 0..319
        int att = (x < 160) ? 1 : 2;
        int m = (att == 1) ? x : x - 160;
        int nsplit = (att == 1) ? 10 : 20;
        const float* base = (att == 1) ? Spart : Spart + 614400;
        int noff = (att == 1) ? 4096 : 4736;
        u16* P = Pb12 + ((att == 1) ? 0 : 102400);
        int i = m >> 5, ro = (m & 31) * 32;
        int n = tid;
        bool act = (n <= m) && (n < 160);
        float myv = 0.f;
        if (act) {
            int t = i * (i + 1) / 2 + (n >> 5);
            const float* src = base + ((long)((b * 15 + t) * nsplit)) * 1024 + ro + (n & 31);
            float s = 0.f;
            for (int sp = 0; sp < nsplit; ++sp) s += src[(long)sp * 1024];
            myv = s / (nq[noff + b * 160 + m] * nk[noff + b * 160 + n]);
        }
        __shared__ float red[256];
        red[tid] = act ? myv : -1e30f; __syncthreads();
        for (int w = 128; w >= 1; w >>= 1) {
            if (tid < w) red[tid] = fmaxf(red[tid], red[tid + w]);
            __syncthreads();
        }
        float mx = red[0]; __syncthreads();
        float e = act ? __expf(myv - mx) : 0.f;
        red[tid] = e; __syncthreads();
        for (int w = 128; w >= 1; w >>= 1) {
            if (tid < w) red[tid] += red[tid + w];
            __syncthreads();
        }
        float inv = 1.f / red[0];
        if (n < 160) P[((long)b * 160 + m) * 160 + n] = f2b(e * inv);
    }
}

// ---------------- K5: fused O-GEMMs + residual (R11 structure) -------------
__global__ __launch_bounds__(256) void k_ogemm_all(
        const u16* __restrict__ Pb, const u16* __restrict__ vt0,
        const u16* __restrict__ Pb12, const u16* __restrict__ vt1,
        const u16* __restrict__ vt2, const u16* __restrict__ kvb,
        u16* __restrict__ catb) {
    // grid (2800, 4): x<400 -> att0; else att1/2
    __shared__ u16 lds[64 * 72 + 32 * 72];   // 13,824 B
    int x = blockIdx.x, b = blockIdx.y;
    int tid = threadIdx.x, w = tid >> 6, l = tid & 63, quad = l >> 4, col = l & 15;
    if (x < 400) {
        int mtt = x & 15, kc = x >> 4;
        int mt = mtt * 64;
        long co = (long)kc * 1024;
        const u16* vtc = vt0 + ((long)b * 25 + kc) * 32 * 1024;
        u16* Ps = lds;              // 64 x 72 (rows m-local, cols p-slab 64)
        u16* Vs = lds + 64 * 72;    // 32 x 72 (rows f-local, cols p-slab 64)
        f4 z = {0.f, 0.f, 0.f, 0.f};
        f4 acc[2]; acc[0] = z; acc[1] = z;
        for (int s = 0; s <= mtt; ++s) {         // p = 0 .. mt+64 (P zero past m)
            int p0 = s * 64;
#pragma unroll
            for (int i = 0; i < 2; ++i) {        // P stage: 64 x 64
                int idx = i * 256 + tid;
                int row = idx >> 3, c8 = (idx & 7) * 8;
                *(bf8*)&Ps[row * 72 + c8] =
                    *(const bf8*)(Pb + ((long)(b * 1024 + mt + row)) * 1024 + p0 + c8);
            }
            {                                    // V stage: 32 x 64
                int f = tid >> 3, p8 = (tid & 7) * 8;
                *(bf8*)&Vs[f * 72 + p8] =
                    *(const bf8*)(vtc + (long)f * 1024 + p0 + p8);
            }
            __syncthreads();
            bf8 a0 = *(bf8*)&Ps[(w * 16 + col) * 72 + quad * 8];
            bf8 a1 = *(bf8*)&Ps[(w * 16 + col) * 72 + 32 + quad * 8];
#pragma unroll
            for (int t2 = 0; t2 < 2; ++t2) {
                bf8 b0 = *(bf8*)&Vs[(t2 * 16 + col) * 72 + quad * 8];
                bf8 b1 = *(bf8*)&Vs[(t2 * 16 + col) * 72 + 32 + quad * 8];
                acc[t2] = MFMA(a0, b0, acc[t2]);
                acc[t2] = MFMA(a1, b1, acc[t2]);
            }
            __syncthreads();
        }
#pragma unroll
        for (int t2 = 0; t2 < 2; ++t2)
#pragma unroll
            for (int r = 0; r < 4; ++r) {
                int m = mt + w * 16 + quad * 4 + r, f = t2 * 16 + col;
                long adr = ((long)(b * 128 + (m >> 5))) * NSP + (m & 31) * 32 + co + f;
                catb[adr] = f2b(acc[t2][r] + b2f(kvb[adr]));
            }
    } else {
        int x2 = x - 400;                        // 0..2399
        int it = x2 % 5, y = x2 / 5;             // y 0..479
        int att, kc, KC; const u16 *vt, *P;
        if (y < 160) { att = 1; kc = y;       KC = 160; vt = vt1; P = Pb12; }
        else         { att = 2; kc = y - 160; KC = 320; vt = vt2; P = Pb12 + 102400; }
        int mt = it * 32;
        const u16* vtc = vt + ((long)b * KC + kc) * 32 * 160;
        u16* Ps = lds;                 // 32*40
        u16* Vs = lds + 32 * 40;       // 32*40
        int mh = w & 1, fh = w >> 1;
        f4 acc = {0.f, 0.f, 0.f, 0.f};
        for (int nt2 = 0; nt2 <= it; ++nt2) {
            {
                int row = tid >> 3, g4 = (tid & 7) * 4;
                *(ushort4*)&Ps[row * 40 + g4] =
                    *(const ushort4*)(P + ((long)(b * 160 + mt + row)) * 160 + nt2 * 32 + g4);
                *(ushort4*)&Vs[row * 40 + g4] =
                    *(const ushort4*)(vtc + (long)row * 160 + nt2 * 32 + g4);
            }
            __syncthreads();
            bf8 a  = *(bf8*)&Ps[(mh * 16 + col) * 40 + quad * 8];
            bf8 bb = *(bf8*)&Vs[(fh * 16 + col) * 40 + quad * 8];
            acc = MFMA(a, bb, acc);
            __syncthreads();
        }
#pragma unroll
        for (int r = 0; r < 4; ++r) {
            int m = mt + mh * 16 + quad * 4 + r, f = fh * 16 + col;
            long adr = row_base(att, b, m) + chunk_off(att, kc) + f;
            catb[adr] = f2b(acc[r] + b2f(kvb[adr]));
        }
    }
}

// ---------------- K6: transpose cat -> ct + fused LN stats -----------------
__global__ __launch_bounds__(256) void k_transpose_ln(
        const u16* __restrict__ catb, u16* __restrict__ ctb,
        float* __restrict__ mu, float* __restrict__ rstd) {
    // grid (64, 100): 16 tokens (hw) x 128 d per block
    int hwt = blockIdx.x * 16, bn = blockIdx.y;
    int b = bn / 25, uv = bn - b * 25;
    __shared__ u16 T[16 * 136];
    int tid = threadIdx.x;
    const u16* src = catb + (long)b * 128 * NSP + (long)uv * HWC + hwt;
    {
        int d = tid >> 1, hw8 = (tid & 1) * 8;
        bf8 v = *(const bf8*)(src + (long)d * NSP + hw8);
#pragma unroll
        for (int j = 0; j < 8; ++j) T[(hw8 + j) * 136 + d] = ((u16*)&v)[j];
    }
    __syncthreads();
    {
        int w = tid >> 6, l = tid & 63;
        int tk = w * 4 + (l >> 4), dg = (l & 15) * 8;
        bf8 vv = *(bf8*)&T[tk * 136 + dg];
        float s = 0.f, s2 = 0.f;
#pragma unroll
        for (int j = 0; j < 8; ++j) {
            float f = b2f(((u16*)&vv)[j]); s += f; s2 += f * f;
        }
        for (int o = 8; o >= 1; o >>= 1) { s += __shfl_xor(s, o); s2 += __shfl_xor(s2, o); }
        if ((l & 15) == 0) {
            int t = bn * 1024 + hwt + tk;
            float m = s * (1.f / 128.f);
            float var = s2 * (1.f / 128.f) - m * m;
            mu[t] = m; rstd[t] = rsqrtf(var + 1e-5f);
        }
    }
    {
        int hw = tid >> 4, d8 = (tid & 15) * 8;
        *(bf8*)(ctb + ((long)(bn * 1024 + hwt + hw)) * 128 + d8) = *(bf8*)&T[hw * 136 + d8];
    }
}

// ---------------- K8: h1 = relu(LN(ct) @ W1) (MFMA) ------------------------
__global__ __launch_bounds__(256) void k_mlp1(
        const u16* __restrict__ ctb, const float* __restrict__ mu,
        const float* __restrict__ rstd, const float* __restrict__ g,
        const float* __restrict__ be, const u16* __restrict__ wbt,
        u16* __restrict__ h1b) {
    int tt = blockIdx.x * 64, tid = threadIdx.x;
    const u16* W1b = wbt + 16384;                // [n][k] 128x128
    __shared__ u16 As[64 * 136], Wt[128 * 136];
    __shared__ float gl[128], bl[128];
    if (tid < 128) { gl[tid] = g[tid]; bl[tid] = be[tid]; }
    for (int q = tid; q < 2048; q += 256) {      // W stage: 16B contiguous
        int n = q >> 4, k8 = (q & 15) * 8;
        *(bf8*)&Wt[n * 136 + k8] = *(const bf8*)(W1b + n * 128 + k8);
    }
    __syncthreads();                             // gl/bl visible
    for (int q = tid; q < 1024; q += 256) {      // A: LN transform, bf8
        int row = q >> 4, k8 = (q & 15) * 8, t = tt + row;
        bf8 cv = *(const bf8*)(ctb + (long)t * 128 + k8);
        float m = mu[t], rs = rstd[t];
        bf8 av;
#pragma unroll
        for (int j = 0; j < 8; ++j)
            ((u16*)&av)[j] = f2b((b2f(((u16*)&cv)[j]) - m) * rs * gl[k8 + j] + bl[k8 + j]);
        *(bf8*)&As[row * 136 + k8] = av;
    }
    __syncthreads();
    int w = tid >> 6, l = tid & 63, quad = l >> 4, col = l & 15;
    f4 z = {0.f, 0.f, 0.f, 0.f};
    f4 acc[8]; for (int i = 0; i < 8; ++i) acc[i] = z;
#pragma unroll
    for (int kc = 0; kc < 4; ++kc) {
        bf8 a = *(bf8*)&As[(w * 16 + col) * 136 + kc * 32 + quad * 8];
#pragma unroll
        for (int nt = 0; nt < 8; ++nt) {
            bf8 bb = *(bf8*)&Wt[(nt * 16 + col) * 136 + kc * 32 + quad * 8];
            acc[nt] = MFMA(a, bb, acc[nt]);
        }
    }
#pragma unroll
    for (int nt = 0; nt < 8; ++nt)
#pragma unroll
        for (int r = 0; r < 4; ++r) {
            int t = tt + w * 16 + quad * 4 + r, n = nt * 16 + col;
            h1b[(long)t * 128 + n] = f2b(fmaxf(acc[nt][r], 0.f));
        }
}

// ---------------- K9: m2 = h1 @ W2 + ct (MFMA) -----------------------------
__global__ __launch_bounds__(256) void k_mlp2(
        const u16* __restrict__ h1b, const u16* __restrict__ ctb,
        const u16* __restrict__ wbt, u16* __restrict__ m2b) {
    int tt = blockIdx.x * 64, tid = threadIdx.x;
    const u16* W2b = wbt + 32768;                // [n][k] 128x128
    __shared__ u16 As[64 * 136], Wt[128 * 136];
    for (int q = tid; q < 2048; q += 256) {
        int n = q >> 4, k8 = (q & 15) * 8;
        *(bf8*)&Wt[n * 136 + k8] = *(const bf8*)(W2b + n * 128 + k8);
    }
    for (int q = tid; q < 1024; q += 256) {
        int row = q >> 4, k8 = (q & 15) * 8;
        *(bf8*)&As[row * 136 + k8] = *(const bf8*)(h1b + (long)(tt + row) * 128 + k8);
    }
    __syncthreads();
    int w = tid >> 6, l = tid & 63, quad = l >> 4, col = l & 15;
    f4 z = {0.f, 0.f, 0.f, 0.f};
    f4 acc[8]; for (int i = 0; i < 8; ++i) acc[i] = z;
#pragma unroll
    for (int kc = 0; kc < 4; ++kc) {
        bf8 a = *(bf8*)&As[(w * 16 + col) * 136 + kc * 32 + quad * 8];
#pragma unroll
        for (int nt = 0; nt < 8; ++nt) {
            bf8 bb = *(bf8*)&Wt[(nt * 16 + col) * 136 + kc * 32 + quad * 8];
            acc[nt] = MFMA(a, bb, acc[nt]);
        }
    }
#pragma unroll
    for (int nt = 0; nt < 8; ++nt)
#pragma unroll
        for (int r = 0; r < 4; ++r) {
            int t = tt + w * 16 + quad * 4 + r, n = nt * 16 + col;
            m2b[(long)t * 128 + n] = f2b(acc[nt][r] + b2f(ctb[(long)t * 128 + n]));
        }
}

// ---------------- K10: out = m2 @ W_out (MFMA), scatter --------------------
__global__ __launch_bounds__(256) void k_out(
        const u16* __restrict__ m2b, const u16* __restrict__ wbt,
        float* __restrict__ out) {
    int tt = blockIdx.x * 64, tid = threadIdx.x;
    const u16* Wob = wbt + 49152;                // [o][k] 64x128
    __shared__ u16 As[64 * 136], Wt[64 * 136];
    for (int q = tid; q < 1024; q += 256) {
        int o = q >> 4, k8 = (q & 15) * 8;
        *(bf8*)&Wt[o * 136 + k8] = *(const bf8*)(Wob + o * 128 + k8);
    }
    for (int q = tid; q < 1024; q += 256) {
        int row = q >> 4, k8 = (q & 15) * 8;
        *(bf8*)&As[row * 136 + k8] = *(const bf8*)(m2b + (long)(tt + row) * 128 + k8);
    }
    __syncthreads();
    int w = tid >> 6, l = tid & 63, quad = l >> 4, col = l & 15;
    f4 z = {0.f, 0.f, 0.f, 0.f};
    f4 acc[4]; for (int i = 0; i < 4; ++i) acc[i] = z;
#pragma unroll
    for (int kc = 0; kc < 4; ++kc) {
        bf8 a = *(bf8*)&As[(w * 16 + col) * 136 + kc * 32 + quad * 8];
#pragma unroll
        for (int nt = 0; nt < 4; ++nt) {
            bf8 bb = *(bf8*)&Wt[(nt * 16 + col) * 136 + kc * 32 + quad * 8];
            acc[nt] = MFMA(a, bb, acc[nt]);
        }
    }
    int t0 = tt + w * 16 + quad * 4;
    int bn = t0 >> 10, hw = t0 & 1023;
    int b = bn / 25, uv = bn - b * 25;
#pragma unroll
    for (int nt = 0; nt < 4; ++nt) {
        int o = nt * 16 + col;
        float4 pk = {acc[nt][0], acc[nt][1], acc[nt][2], acc[nt][3]};
        *(float4*)(out + ((long)((b * 64 + o) * 25 + uv)) * 1024 + hw) = pk;
    }
}

// ---------------- launch ---------------------------------------------------
extern "C" void kernel_launch(void* const* d_in, const int* in_sizes, int n_in,
                              void* d_out, int out_size, void* d_ws, size_t ws_size,
                              hipStream_t stream) {
    const float* x_lf = (const float*)d_in[0];
    const float* x_hf = (const float*)d_in[1];
    const float* W_in = (const float*)d_in[2];
    const float* W_kv = (const float*)d_in[3];
    const float* ln_g = (const float*)d_in[4];
    const float* ln_b = (const float*)d_in[5];
    const float* W_m1 = (const float*)d_in[6];
    const float* W_m2 = (const float*)d_in[7];
    const float* W_ot = (const float*)d_in[8];
    float* out = (float*)d_out;

    float* ws = (float*)d_ws;
    u16*   qb    = (u16*)ws;
    u16*   h1b   = qb;                                // reuse after attention
    u16*   kvb   = (u16*)(ws + 6553600);
    u16*   m2b   = kvb;                               // reuse after attention
    u16*   catb  = (u16*)(ws + 13107200);
    u16*   ctb   = (u16*)(ws + 19660800);
    u16*   Sb    = (u16*)(ws + 26214400);
    u16*   Pb    = (u16*)(ws + 28311552);
    u16*   Pb12  = (u16*)(ws + 30408704);
    float* Spart = ws + 30511104;                     // att1@0, att2@614400
    float* nq    = ws + 32354304;                     // att0@0,att1@4096,att2@4736
    float* nk    = ws + 32359680;
    float* mu    = ws + 32365056;
    float* rstd  = ws + 32467456;
    u16*   vt0   = (u16*)(ws + 32569856);             // ends 34,208,256
    u16*   vt1   = (u16*)(ws + 34208256);             // ends 35,846,656
    u16*   vt2   = (u16*)(ws + 35846656);             // ends 39,123,456
    u16*   wbt   = (u16*)(ws + 39123456);             // after vt2

    // 0. one-time weight conversion
    k_prep<<<dim3(224), 256, 0, stream>>>(W_in, W_kv, W_m1, W_m2, W_ot, wbt);

    // 1. token GEMMs -> bf16 q/kv
    k_tokens<<<dim3(400, 4, 2), 256, 0, stream>>>(x_hf, x_lf, wbt, qb, kvb);

    // 2. fused V^T + norms (wave-per-row, bf8 loads)
    k_vt_norms<<<dim3(3872, 4), 256, 0, stream>>>(qb, kvb, vt0, vt1, vt2, nq, nk);

    // 3. fused S-GEMMs
    k_sgemm_all<<<dim3(586, 4), 256, 0, stream>>>(qb, kvb, nq, nk, Sb, Spart);

    // 4. fused softmaxes
    k_softmax_all<<<dim3(576, 4), 256, 0, stream>>>(Sb, Pb, Spart, nq, nk, Pb12);

    // 5. fused O-GEMMs + residual
    k_ogemm_all<<<dim3(2800, 4), 256, 0, stream>>>(Pb, vt0, Pb12, vt1, vt2, kvb, catb);

    // 6. transpose to token-major + LN stats
    k_transpose_ln<<<dim3(64, 100), 256, 0, stream>>>(catb, ctb, mu, rstd);

    // 7. MLP + out projection
    k_mlp1<<<dim3(1600), 256, 0, stream>>>(ctb, mu, rstd, ln_g, ln_b, wbt, h1b);
    k_mlp2<<<dim3(1600), 256, 0, stream>>>(h1b, ctb, wbt, m2b);
    k_out <<<dim3(1600), 256, 0, stream>>>(m2b, wbt, out);
}